// Round 1
// baseline (2588.746 us; speedup 1.0000x reference)
//
#include <hip/hip_runtime.h>
#include <hip/hip_bf16.h>
#include <math.h>

typedef __attribute__((ext_vector_type(8))) short bf16x8;
typedef __attribute__((ext_vector_type(4))) float f32x4;
typedef unsigned short u16;
typedef unsigned int u32;

#define NN 370
#define HH 64
#define LL 8
#define TT 64
#define BTOT 512            // B*T
#define RR (BTOT*NN)        // 189440 rows
#define KTOPK 37
#define SPLITK 10

// ---------- helpers ----------
__device__ inline u16 f2bf(float f){
  __hip_bfloat16 h = __float2bfloat16(f);
  return __builtin_bit_cast(u16, h);
}
__device__ inline float bf2f(short s){
  u32 v = ((u32)(u16)s) << 16;
  return __builtin_bit_cast(float, v);
}
__device__ inline float gelu_f(float x){ return 0.5f * x * (1.0f + erff(x * 0.70710678118654752440f)); }

// swizzled LDS store/load of 16B (8 bf16). stride must be a multiple of 128 bytes.
__device__ inline void sts16(char* lds, int row, int kb, int stride, bf16x8 v){
  *reinterpret_cast<bf16x8*>(lds + row*stride + (kb ^ ((row&7)<<4))) = v;
}
__device__ inline bf16x8 lds16(const char* lds, int row, int kb, int stride){
  return *reinterpret_cast<const bf16x8*>(lds + row*stride + (kb ^ ((row&7)<<4)));
}
__device__ inline void copyB(char* dst, const u16* src, int bytes, int tid, int nthr){
  for(int o = tid*16; o < bytes; o += nthr*16)
    *reinterpret_cast<bf16x8*>(dst + o) =
      *reinterpret_cast<const bf16x8*>(reinterpret_cast<const char*>(src) + o);
}

// MFMA core: one 16-row M-tile (mt) x NT 16-col tiles, K = KT*32, A/B both swizzled LDS.
template<int NT, int KT>
__device__ inline void mma_core(const char* sA, const char* sB, int strideA, int strideB,
                                f32x4* acc, int ln, int mt){
#pragma unroll
  for(int nt=0; nt<NT; ++nt) acc[nt] = f32x4{0.f,0.f,0.f,0.f};
#pragma unroll
  for(int kt=0; kt<KT; ++kt){
    int kb = kt*64 + ((ln>>4)<<4);
    bf16x8 a = lds16(sA, mt*16 + (ln&15), kb, strideA);
#pragma unroll
    for(int nt=0; nt<NT; ++nt){
      bf16x8 b = lds16(sB, nt*16 + (ln&15), kb, strideB);
      acc[nt] = __builtin_amdgcn_mfma_f32_16x16x32_bf16(a, b, acc[nt], 0, 0, 0);
    }
  }
}

// stage 64 rows x 64 cols (fp32 source) -> bf16 swizzled LDS, stride 128B
template<bool DOGELU>
__device__ inline void stageA_f32(char* sA, const float* src, int tid, int nthr){
  for(int s = tid; s < 512; s += nthr){
    int row = s >> 3, ks = s & 7;
    const float4* p = reinterpret_cast<const float4*>(src + row*64 + ks*8);
    float4 a = p[0], b = p[1];
    float f[8] = {a.x,a.y,a.z,a.w,b.x,b.y,b.z,b.w};
    if(DOGELU){
#pragma unroll
      for(int i=0;i<8;i++) f[i] = gelu_f(f[i]);
    }
    bf16x8 v;
#pragma unroll
    for(int i=0;i<8;i++) v[i] = (short)f2bf(f[i]);
    sts16(sA, row, ks*16, 128, v);
  }
}
template<bool DOGELU>
__device__ inline void stageA_bf16(char* sA, const u16* src, int tid, int nthr){
  for(int s = tid; s < 512; s += nthr){
    int row = s >> 3, ks = s & 7;
    bf16x8 v = *reinterpret_cast<const bf16x8*>(src + row*64 + ks*8);
    if(DOGELU){
#pragma unroll
      for(int i=0;i<8;i++) v[i] = (short)f2bf(gelu_f(bf2f(v[i])));
    }
    sts16(sA, row, ks*16, 128, v);
  }
}

// ---------- prep kernels ----------
__global__ void kzero(float* __restrict__ p, size_t n){
  for(size_t i = (size_t)blockIdx.x*256 + threadIdx.x; i < n; i += (size_t)gridDim.x*256) p[i] = 0.f;
}

__global__ void kbuildA(const int* __restrict__ ei, const float* __restrict__ ew, float* __restrict__ Araw, int E){
  int e = blockIdx.x*256 + threadIdx.x;
  if(e < E){
    int src = ei[e], dst = ei[E + e];
    atomicAdd(&Araw[dst*NN + src], ew[e]);
  }
}

__global__ __launch_bounds__(384) void knormF(float* __restrict__ Araw, float* __restrict__ dinvF){
  int i = threadIdx.x;
  if(i < NN){
    float d0 = Araw[i*NN+i];
    if(d0 == 0.f) Araw[i*NN+i] = 1.f;
    float s = 0.f;
    for(int j=0;j<NN;++j) s += Araw[i*NN+j];
    dinvF[i] = rsqrtf(s);
  }
}

// adaptive adjacency: one block per (row i, layer l); exact jax top_k tie-breaking
__global__ __launch_bounds__(384) void kadapt(const float* __restrict__ esrc, const float* __restrict__ etgt,
                                              float* __restrict__ ArawA, float* __restrict__ dinvA){
  __shared__ float tg[NN*16];
  __shared__ float sv[NN];
  __shared__ float red[8];
  int i = blockIdx.x, l = blockIdx.y, tid = threadIdx.x;
  const float* Et = etgt + (size_t)l*NN*16;
  for(int idx = tid; idx < NN*16; idx += 384) tg[idx] = Et[idx];
  float sr[16];
  const float* Es = esrc + ((size_t)l*NN + i)*16;
#pragma unroll
  for(int k=0;k<16;k++) sr[k] = Es[k];
  __syncthreads();
  bool act = tid < NN;
  float s = 0.f;
  if(act){
    float d = 0.f;
#pragma unroll
    for(int k=0;k<16;k++) d += sr[k]*tg[tid*16+k];
    s = fmaxf(d, 0.f);
  }
  // block max
  float v = act ? s : -1.f;
#pragma unroll
  for(int o=1;o<64;o<<=1) v = fmaxf(v, __shfl_xor(v,o,64));
  if((tid&63)==0) red[tid>>6] = v;
  __syncthreads();
  float mx = fmaxf(fmaxf(fmaxf(red[0],red[1]),fmaxf(red[2],red[3])),fmaxf(red[4],red[5]));
  __syncthreads();
  float e = act ? expf(s - mx) : 0.f;
  float t = e;
#pragma unroll
  for(int o=1;o<64;o<<=1) t += __shfl_xor(t,o,64);
  if((tid&63)==0) red[tid>>6] = t;
  __syncthreads();
  float sum = red[0]+red[1]+red[2]+red[3]+red[4]+red[5];
  float p = e / sum;
  if(act) sv[tid] = p;
  __syncthreads();
  float val = 0.f;
  if(act){
    int cnt = 0;
    for(int k=0;k<NN;++k){
      float pk = sv[k];
      cnt += ((pk > p) || (pk == p && k < tid)) ? 1 : 0;
    }
    val = (cnt < KTOPK) ? p : 0.f;
    if(tid == i && val == 0.f) val = 1.f;   // self-loop where diag missing
  }
  float dsum = val;
#pragma unroll
  for(int o=1;o<64;o<<=1) dsum += __shfl_xor(dsum,o,64);
  __syncthreads();
  if((tid&63)==0) red[tid>>6] = dsum;
  __syncthreads();
  float deg = red[0]+red[1]+red[2]+red[3]+red[4]+red[5];
  if(tid == 0) dinvA[l*NN + i] = rsqrtf(deg);
  if(act) ArawA[((size_t)l*NN + i)*NN + tid] = val;
}

// build normalized dense bf16 A_cat[l] = [A_fixed(384) | A_adapt(384)] over k=768
__global__ void kacat(const float* __restrict__ Araw, const float* __restrict__ ArawA,
                      const float* __restrict__ dinvF, const float* __restrict__ dinvA,
                      u16* __restrict__ Acat){
  int idx = blockIdx.x*256 + threadIdx.x;
  if(idx >= LL*384*768) return;
  int k = idx % 768; int m = (idx / 768) % 384; int l = idx / (768*384);
  float v = 0.f;
  if(m < NN){
    if(k < 384){
      if(k < NN) v = dinvF[m]*Araw[m*NN+k]*dinvF[k];
    } else {
      int n = k - 384;
      if(n < NN) v = dinvA[l*NN+m]*ArawA[((size_t)l*NN+m)*NN+n]*dinvA[l*NN+n];
    }
  }
  Acat[idx] = f2bf(v);
}

// pre-transposed + pre-swizzled weight tiles Bt[col][k]
__global__ void kbt_small(const float* __restrict__ inW, const float* __restrict__ e1W, const float* __restrict__ e2W,
                          u16* __restrict__ BtIN, u16* __restrict__ BtE1, u16* __restrict__ BtE2){
  const float* W = blockIdx.x==0 ? inW : (blockIdx.x==1 ? e1W : e2W);
  u16* Bt = blockIdx.x==0 ? BtIN : (blockIdx.x==1 ? BtE1 : BtE2);
  for(int idx = threadIdx.x; idx < 4096; idx += 256){
    int c = idx >> 6, k = idx & 63;
    *(u16*)((char*)Bt + c*128 + ((k*2) ^ ((c&7)<<4))) = f2bf(W[k*64 + c]);
  }
}

__global__ void kbt_layer(const float* __restrict__ gcnfW, const float* __restrict__ gcnaW,
                          const float* __restrict__ filtW, const float* __restrict__ gateW,
                          const float* __restrict__ skipW, const float* __restrict__ resW,
                          u16* __restrict__ BtUV, u16* __restrict__ BtCV, u16* __restrict__ BtSR){
  int l = blockIdx.x, which = blockIdx.y;
  if(which == 0){            // [Wf | Wa] : 128 cols x 64 k
    u16* Bt = BtUV + (size_t)l*128*64;
    for(int idx=threadIdx.x; idx<8192; idx+=256){
      int c = idx>>6, k = idx&63;
      float v = (c<64) ? gcnfW[(size_t)l*4096 + k*64 + c] : gcnaW[(size_t)l*4096 + k*64 + (c-64)];
      *(u16*)((char*)Bt + c*128 + ((k*2) ^ ((c&7)<<4))) = f2bf(v);
    }
  } else if(which == 1){     // conv [filt | gate] : 128 cols x 128 k (k<64: cur tap1, k>=64: prev tap0)
    u16* Bt = BtCV + (size_t)l*128*128;
    for(int idx=threadIdx.x; idx<16384; idx+=256){
      int c = idx>>7, k = idx&127;
      const float* W = (c<64) ? filtW : gateW;
      int o = c & 63, ii = k & 63, tap = (k<64) ? 1 : 0;
      float v = W[(size_t)l*8192 + o*128 + ii*2 + tap];
      *(u16*)((char*)Bt + c*256 + ((k*2) ^ ((c&7)<<4))) = f2bf(v);
    }
  } else {                   // [skip | res] : 128 cols x 64 k
    u16* Bt = BtSR + (size_t)l*128*64;
    for(int idx=threadIdx.x; idx<8192; idx+=256){
      int c = idx>>6, k = idx&63;
      float v = (c<64) ? skipW[(size_t)l*4096 + c*64 + k] : resW[(size_t)l*4096 + (c-64)*64 + k];
      *(u16*)((char*)Bt + c*128 + ((k*2) ^ ((c&7)<<4))) = f2bf(v);
    }
  }
}

// eeg1_W (23680x256 fp32) -> Wt (256 x 23680 bf16)
__global__ void ktrans(const float* __restrict__ W, u16* __restrict__ Wt){
  __shared__ float tile[64][65];
  int kb = blockIdx.x*64, cb = blockIdx.y*64;
  for(int idx = threadIdx.x; idx < 4096; idx += 256){
    int kk = idx>>6, cc = idx&63;
    tile[kk][cc] = W[(size_t)(kb+kk)*256 + cb+cc];
  }
  __syncthreads();
  for(int idx = threadIdx.x; idx < 4096; idx += 256){
    int cc = idx>>6, kk = idx&63;
    Wt[(size_t)(cb+cc)*23680 + kb+kk] = f2bf(tile[kk][cc]);
  }
}

// ---------- main pipeline kernels ----------
__global__ __launch_bounds__(256) void krowmm_in(const float* __restrict__ X, const u16* __restrict__ Bt,
                                                 const float* __restrict__ bias, float* __restrict__ out){
  __shared__ char sA[8192];
  __shared__ char sB[8192];
  int tid = threadIdx.x;
  copyB(sB, Bt, 8192, tid, 256);
  stageA_f32<false>(sA, X + (size_t)blockIdx.x*4096, tid, 256);
  __syncthreads();
  int w = tid>>6, ln = tid&63;
  f32x4 acc[4];
  mma_core<4,2>(sA, sB, 128, 128, acc, ln, w);
  size_t rbase = (size_t)blockIdx.x*64 + w*16 + ((ln>>4)<<2);
#pragma unroll
  for(int nt=0; nt<4; ++nt){
    int c = nt*16 + (ln&15);
    float bv = bias[c];
#pragma unroll
    for(int r=0;r<4;++r) out[(rbase+r)*64 + c] = acc[nt][r] + bv;
  }
}

__global__ __launch_bounds__(256) void krowmm_uv(const float* __restrict__ X, const u16* __restrict__ Bt,
                                                 u16* __restrict__ t1){
  __shared__ char sA[8192];
  __shared__ char sB[16384];
  int tid = threadIdx.x;
  copyB(sB, Bt, 16384, tid, 256);
  stageA_f32<false>(sA, X + (size_t)blockIdx.x*4096, tid, 256);
  __syncthreads();
  int w = tid>>6, ln = tid&63;
  f32x4 acc[8];
  mma_core<8,2>(sA, sB, 128, 128, acc, ln, w);
  size_t rbase = (size_t)blockIdx.x*64 + w*16 + ((ln>>4)<<2);
#pragma unroll
  for(int nt=0; nt<8; ++nt){
    int c = nt*16 + (ln&15);
#pragma unroll
    for(int r=0;r<4;++r) t1[(rbase+r)*128 + c] = f2bf(acc[nt][r]);
  }
}

// per-(b,t): OUT(370x64) = A_cat(370x768) @ [U;V](768x64), + (gcnf_b + gcna_b)
__global__ __launch_bounds__(512) void kspmm(const u16* __restrict__ t1, const u16* __restrict__ Acat,
                                             const float* __restrict__ bfb, const float* __restrict__ bab,
                                             u16* __restrict__ t2){
  __shared__ char uvt[64*768];   // 48KB: UVt[h][k] for one 384-k phase
  int bt = blockIdx.x, tid = threadIdx.x;
  int w = tid>>6, ln = tid&63;
  f32x4 acc[12];
#pragma unroll
  for(int j=0;j<12;j++) acc[j] = f32x4{0.f,0.f,0.f,0.f};
  const u16* src = t1 + (size_t)bt*NN*128;
  for(int p=0; p<2; ++p){
    __syncthreads();
    // transpose-stage: UVt[h][n] = t1[n][p*64+h]
    for(int idx = tid; idx < NN*64; idx += 512){
      int n = idx >> 6, c0 = idx & 63;
      u16 v = src[n*128 + p*64 + c0];
      *(u16*)(uvt + c0*768 + ((n*2) ^ ((c0&7)<<4))) = v;
    }
    for(int idx = tid; idx < 64*14; idx += 512){   // zero pad k in [370,384)
      int c0 = idx / 14, kk = NN + idx % 14;
      *(u16*)(uvt + c0*768 + ((kk*2) ^ ((c0&7)<<4))) = 0;
    }
    __syncthreads();
#pragma unroll
    for(int jj=0; jj<12; ++jj){
      int j = w*12 + jj;
      int mt = j >> 2, nt = j & 3;
      const char* arow = (const char*)Acat + (size_t)(mt*16 + (ln&15))*1536 + p*768 + ((ln>>4)<<4);
      int brw = nt*16 + (ln&15);
      const char* brow = uvt + brw*768;
      int bx = (brw & 7) << 4;
      f32x4 a4 = acc[jj];
#pragma unroll
      for(int kt=0; kt<12; ++kt){
        bf16x8 a = *reinterpret_cast<const bf16x8*>(arow + kt*64);
        bf16x8 b = *reinterpret_cast<const bf16x8*>(brow + ((kt*64 + ((ln>>4)<<4)) ^ bx));
        a4 = __builtin_amdgcn_mfma_f32_16x16x32_bf16(a, b, a4, 0, 0, 0);
      }
      acc[jj] = a4;
    }
  }
#pragma unroll
  for(int jj=0; jj<12; ++jj){
    int j = w*12 + jj;
    int mt = j >> 2, nt = j & 3;
    int col = nt*16 + (ln&15);
    float bias = bfb[col] + bab[col];
    int mbase = mt*16 + ((ln>>4)<<2);
#pragma unroll
    for(int r=0;r<4;++r){
      int m = mbase + r;
      if(m < NN) t2[((size_t)bt*NN + m)*64 + col] = f2bf(acc[jj][r] + bias);
    }
  }
}

// gated causal conv: out = tanh(filt)*sigmoid(gate); A rows = [h(t) ; h(t-dil)]
__global__ __launch_bounds__(256) void kconv(const u16* __restrict__ t2, const u16* __restrict__ Bt,
                                             const float* __restrict__ fb, const float* __restrict__ gb,
                                             u16* __restrict__ t3, int dil){
  __shared__ char sA[64*256];    // 16KB
  __shared__ char sB[128*256];   // 32KB
  int blk = blockIdx.x, tid = threadIdx.x;
  copyB(sB, Bt, 32768, tid, 256);
  int r0 = blk*64;
  for(int s = tid; s < 1024; s += 256){
    int row = s >> 4, sc = s & 15;
    int r = r0 + row;
    bf16x8 v;
    if(sc < 8){
      v = *reinterpret_cast<const bf16x8*>(t2 + (size_t)r*64 + sc*8);
    } else {
      int t = (r / NN) % TT;
      if(t >= dil) v = *reinterpret_cast<const bf16x8*>(t2 + (size_t)(r - dil*NN)*64 + (sc-8)*8);
      else { bf16x8 z = {0,0,0,0,0,0,0,0}; v = z; }
    }
    sts16(sA, row, sc*16, 256, v);
  }
  __syncthreads();
  int w = tid>>6, ln = tid&63;
  f32x4 acc[8];
  mma_core<8,4>(sA, sB, 256, 256, acc, ln, w);
  size_t rbase = (size_t)r0 + w*16 + ((ln>>4)<<2);
#pragma unroll
  for(int nt=0; nt<4; ++nt){
    int o = nt*16 + (ln&15);
    float fbv = fb[o], gbv = gb[o];
#pragma unroll
    for(int r=0;r<4;++r){
      float fv = acc[nt][r] + fbv;
      float gv = acc[nt+4][r] + gbv;
      float ov = tanhf(fv) * (1.f/(1.f + expf(-gv)));
      t3[(rbase+r)*64 + o] = f2bf(ov);
    }
  }
}

// fused skip/res 1x1 convs + residual + LayerNorm + skip accumulation
__global__ __launch_bounds__(256) void ksr(const u16* __restrict__ t3, const u16* __restrict__ Bt,
                                           const float* __restrict__ sb, const float* __restrict__ rb,
                                           const float* __restrict__ lng, const float* __restrict__ lnb,
                                           float* __restrict__ xbuf, float* __restrict__ skip, int first){
  __shared__ char sA[8192];
  __shared__ char sB[16384];
  __shared__ float stg[64][128];
  int tid = threadIdx.x;
  copyB(sB, Bt, 16384, tid, 256);
  stageA_bf16<false>(sA, t3 + (size_t)blockIdx.x*4096, tid, 256);
  __syncthreads();
  int w = tid>>6, ln = tid&63;
  f32x4 acc[8];
  mma_core<8,2>(sA, sB, 128, 128, acc, ln, w);
  int lrbase = w*16 + ((ln>>4)<<2);
#pragma unroll
  for(int nt=0; nt<8; ++nt){
    int c = nt*16 + (ln&15);
#pragma unroll
    for(int r=0;r<4;++r) stg[lrbase+r][c] = acc[nt][r];
  }
  __syncthreads();
  size_t r0 = (size_t)blockIdx.x*64;
  for(int rr=0; rr<16; ++rr){
    int lrow = w*16 + rr;
    size_t gi = (r0 + lrow)*64 + ln;
    float s  = stg[lrow][ln]    + sb[ln];
    float re = stg[lrow][64+ln] + rb[ln];
    float y = re + xbuf[gi];
    float t = y;
#pragma unroll
    for(int o=1;o<64;o<<=1) t += __shfl_xor(t, o, 64);
    float m = t * (1.f/64.f);
    float d = y - m;
    float q = d*d;
#pragma unroll
    for(int o=1;o<64;o<<=1) q += __shfl_xor(q, o, 64);
    float vv = q * (1.f/64.f);
    float xo = d * rsqrtf(vv + 1e-5f) * lng[ln] + lnb[ln];
    xbuf[gi] = xo;
    if(first) skip[gi] = s; else skip[gi] += s;
  }
}

__global__ __launch_bounds__(256) void kend_f32(const float* __restrict__ X, const u16* __restrict__ Bt,
                                                const float* __restrict__ bias, u16* __restrict__ out){
  __shared__ char sA[8192];
  __shared__ char sB[8192];
  int tid = threadIdx.x;
  copyB(sB, Bt, 8192, tid, 256);
  stageA_f32<true>(sA, X + (size_t)blockIdx.x*4096, tid, 256);
  __syncthreads();
  int w = tid>>6, ln = tid&63;
  f32x4 acc[4];
  mma_core<4,2>(sA, sB, 128, 128, acc, ln, w);
  size_t rbase = (size_t)blockIdx.x*64 + w*16 + ((ln>>4)<<2);
#pragma unroll
  for(int nt=0; nt<4; ++nt){
    int c = nt*16 + (ln&15);
    float bv = bias[c];
#pragma unroll
    for(int r=0;r<4;++r) out[(rbase+r)*64 + c] = f2bf(acc[nt][r] + bv);
  }
}

__global__ __launch_bounds__(256) void kend_bf16(const u16* __restrict__ X, const u16* __restrict__ Bt,
                                                 const float* __restrict__ bias, u16* __restrict__ out){
  __shared__ char sA[8192];
  __shared__ char sB[8192];
  int tid = threadIdx.x;
  copyB(sB, Bt, 8192, tid, 256);
  stageA_bf16<true>(sA, X + (size_t)blockIdx.x*4096, tid, 256);
  __syncthreads();
  int w = tid>>6, ln = tid&63;
  f32x4 acc[4];
  mma_core<4,2>(sA, sB, 128, 128, acc, ln, w);
  size_t rbase = (size_t)blockIdx.x*64 + w*16 + ((ln>>4)<<2);
#pragma unroll
  for(int nt=0; nt<4; ++nt){
    int c = nt*16 + (ln&15);
    float bv = bias[c];
#pragma unroll
    for(int r=0;r<4;++r) out[(rbase+r)*64 + c] = f2bf(acc[nt][r] + bv);
  }
}

// eeg1: (512 x 23680) @ (23680 x 256), split-K partials (deterministic, no atomics)
__global__ __launch_bounds__(512) void keeg1(const u16* __restrict__ h2, const u16* __restrict__ WtE,
                                             float* __restrict__ part){
  __shared__ char sA[64*128];    // 8KB (padded stride)
  __shared__ char sB[256*128];   // 32KB
  int rowg = blockIdx.x, sp = blockIdx.y;
  int tid = threadIdx.x, w = tid>>6, ln = tid&63;
  f32x4 acc[8];
#pragma unroll
  for(int i=0;i<8;i++) acc[i] = f32x4{0.f,0.f,0.f,0.f};
  int mt = w & 3, ntb = (w>>2)*8;
  for(int ks=0; ks<74; ++ks){
    int k0 = (sp*74 + ks)*32;
    __syncthreads();
    for(int s = tid; s < 256; s += 512){
      int row = s>>2, kc = s&3;
      bf16x8 v = *reinterpret_cast<const bf16x8*>(h2 + (size_t)(rowg*64+row)*23680 + k0 + kc*8);
      sts16(sA, row, kc*16, 128, v);
    }
    for(int s = tid; s < 1024; s += 512){
      int row = s>>2, kc = s&3;
      bf16x8 v = *reinterpret_cast<const bf16x8*>(WtE + (size_t)row*23680 + k0 + kc*8);
      sts16(sB, row, kc*16, 128, v);
    }
    __syncthreads();
    bf16x8 a = lds16(sA, mt*16 + (ln&15), ((ln>>4)<<4), 128);
#pragma unroll
    for(int j=0;j<8;++j){
      bf16x8 b = lds16(sB, (ntb+j)*16 + (ln&15), ((ln>>4)<<4), 128);
      acc[j] = __builtin_amdgcn_mfma_f32_16x16x32_bf16(a, b, acc[j], 0, 0, 0);
    }
  }
  float* dst = part + ((size_t)sp*512 + rowg*64)*256;
#pragma unroll
  for(int j=0;j<8;++j){
    int c = (ntb+j)*16 + (ln&15);
#pragma unroll
    for(int r=0;r<4;++r){
      int row = mt*16 + ((ln>>4)<<2) + r;
      dst[(size_t)row*256 + c] = acc[j][r];
    }
  }
}

// reduce partials + bias + gelu, then @ eeg2_W + b2 -> output (fp32)
__global__ __launch_bounds__(256) void keeg2(const float* __restrict__ part, const float* __restrict__ b1,
                                             const float* __restrict__ W2, const float* __restrict__ b2,
                                             float* __restrict__ out){
  __shared__ float u[256];
  __shared__ float pr[4][64];
  int bt = blockIdx.x, tid = threadIdx.x;
  float sacc = 0.f;
  for(int sp2=0; sp2<SPLITK; ++sp2) sacc += part[((size_t)sp2*512 + bt)*256 + tid];
  u[tid] = gelu_f(sacc + b1[tid]);
  __syncthreads();
  int w = tid>>6, ln = tid&63;
  float acc = 0.f;
  for(int c = w*64; c < (w+1)*64; ++c) acc += u[c] * W2[c*64 + ln];
  pr[w][ln] = acc;
  __syncthreads();
  if(tid < 64)
    out[(size_t)bt*64 + tid] = pr[0][tid]+pr[1][tid]+pr[2][tid]+pr[3][tid] + b2[tid];
}

// ---------- launcher ----------
extern "C" void kernel_launch(void* const* d_in, const int* in_sizes, int n_in,
                              void* d_out, int out_size, void* d_ws, size_t ws_size,
                              hipStream_t stream){
  const float* x_in  = (const float*)d_in[0];
  const int*   ei    = (const int*)d_in[1];
  const float* ew    = (const float*)d_in[2];
  const float* in_W  = (const float*)d_in[3];
  const float* in_b  = (const float*)d_in[4];
  const float* gcnfW = (const float*)d_in[5];
  const float* gcnfb = (const float*)d_in[6];
  const float* esrc  = (const float*)d_in[7];
  const float* etgt  = (const float*)d_in[8];
  const float* gcnaW = (const float*)d_in[9];
  const float* gcnab = (const float*)d_in[10];
  const float* filtW = (const float*)d_in[11];
  const float* filtb = (const float*)d_in[12];
  const float* gateW = (const float*)d_in[13];
  const float* gateb = (const float*)d_in[14];
  const float* resW  = (const float*)d_in[15];
  const float* resb  = (const float*)d_in[16];
  const float* skipW = (const float*)d_in[17];
  const float* skipb = (const float*)d_in[18];
  const float* lng   = (const float*)d_in[19];
  const float* lnb   = (const float*)d_in[20];
  const float* e1W   = (const float*)d_in[21];
  const float* e1b   = (const float*)d_in[22];
  const float* e2W   = (const float*)d_in[23];
  const float* e2b   = (const float*)d_in[24];
  const float* eg1W  = (const float*)d_in[25];
  const float* eg1b  = (const float*)d_in[26];
  const float* eg2W  = (const float*)d_in[27];
  const float* eg2b  = (const float*)d_in[28];
  int E = in_sizes[2];

  char* p = (char*)d_ws;
  auto carve = [&](size_t bytes)->char*{ char* r = p; p += (bytes + 255) & ~(size_t)255; return r; };
  float* xbuf  = (float*)carve((size_t)RR*64*4);
  float* skip  = (float*)carve((size_t)RR*64*4);
  u16*   t1    = (u16*)  carve((size_t)RR*128*2);
  u16*   t2    = (u16*)  carve((size_t)RR*64*2);
  u16*   t3    = (u16*)  carve((size_t)RR*64*2);
  float* Araw9 = (float*)carve((size_t)9*NN*NN*4);   // [fixed | 8 adaptive raw]
  float* Araw  = Araw9;
  float* ArawA = Araw9 + (size_t)NN*NN;
  float* dinvF = (float*)carve(NN*4);
  float* dinvA = (float*)carve(LL*NN*4);
  u16*   Acat  = (u16*)  carve((size_t)LL*384*768*2);
  u16*   BtUV  = (u16*)  carve((size_t)LL*128*64*2);
  u16*   BtCV  = (u16*)  carve((size_t)LL*128*128*2);
  u16*   BtSR  = (u16*)  carve((size_t)LL*128*64*2);
  u16*   BtIN  = (u16*)  carve(64*64*2);
  u16*   BtE1  = (u16*)  carve(64*64*2);
  u16*   BtE2  = (u16*)  carve(64*64*2);
  u16*   WtE   = (u16*)  carve((size_t)256*23680*2);
  float* part  = (float*)carve((size_t)SPLITK*512*256*4);
  u16* h1 = t1;                       // overlay: t1 unused after layer loop
  u16* h2 = t1 + (size_t)RR*64;

  // --- prep ---
  kzero<<<1024, 256, 0, stream>>>(Araw9, (size_t)9*NN*NN);
  kbuildA<<<(E+255)/256, 256, 0, stream>>>(ei, ew, Araw, E);
  knormF<<<1, 384, 0, stream>>>(Araw, dinvF);
  kadapt<<<dim3(NN, LL), 384, 0, stream>>>(esrc, etgt, ArawA, dinvA);
  kacat<<<(LL*384*768 + 255)/256, 256, 0, stream>>>(Araw, ArawA, dinvF, dinvA, Acat);
  kbt_small<<<3, 256, 0, stream>>>(in_W, e1W, e2W, BtIN, BtE1, BtE2);
  kbt_layer<<<dim3(LL, 3), 256, 0, stream>>>(gcnfW, gcnaW, filtW, gateW, skipW, resW, BtUV, BtCV, BtSR);
  ktrans<<<dim3(370, 4), 256, 0, stream>>>(eg1W, WtE);

  // --- input proj ---
  krowmm_in<<<RR/64, 256, 0, stream>>>(x_in, BtIN, in_b, xbuf);

  // --- layers ---
  for(int l=0; l<LL; ++l){
    int dil = 1 << (l & 3);
    krowmm_uv<<<RR/64, 256, 0, stream>>>(xbuf, BtUV + (size_t)l*8192, t1);
    kspmm<<<BTOT, 512, 0, stream>>>(t1, Acat + (size_t)l*384*768, gcnfb + l*64, gcnab + l*64, t2);
    kconv<<<RR/64, 256, 0, stream>>>(t2, BtCV + (size_t)l*16384, filtb + l*64, gateb + l*64, t3, dil);
    ksr<<<RR/64, 256, 0, stream>>>(t3, BtSR + (size_t)l*8192, skipb + l*64, resb + l*64,
                                   lng + l*64, lnb + l*64, xbuf, skip, l==0 ? 1 : 0);
  }

  // --- tail ---
  kend_f32<<<RR/64, 256, 0, stream>>>(skip, BtE1, e1b, h1);
  kend_bf16<<<RR/64, 256, 0, stream>>>(h1, BtE2, e2b, h2);
  keeg1<<<dim3(8, SPLITK), 512, 0, stream>>>(h2, WtE, part);
  keeg2<<<BTOT, 256, 0, stream>>>(part, eg1b, eg2W, eg2b, (float*)d_out);
}

// Round 2
// 2046.377 us; speedup vs baseline: 1.2650x; 1.2650x over previous
//
#include <hip/hip_runtime.h>
#include <hip/hip_bf16.h>
#include <math.h>

typedef __attribute__((ext_vector_type(8))) short bf16x8;
typedef __attribute__((ext_vector_type(4))) short s16x4;
typedef __attribute__((ext_vector_type(4))) float f32x4;
typedef unsigned short u16;
typedef unsigned int u32;

#define NN 370
#define HH 64
#define LL 8
#define TT 64
#define BTOT 512            // B*T
#define RR (BTOT*NN)        // 189440 rows
#define KTOPK 37
#define SPLITK 10
#define T1TSTRIDE 49152     // 128*384 elements per bt in t1T

// ---------- helpers ----------
__device__ inline u16 f2bf(float f){
  __hip_bfloat16 h = __float2bfloat16(f);
  return __builtin_bit_cast(u16, h);
}
__device__ inline float bf2f(short s){
  u32 v = ((u32)(u16)s) << 16;
  return __builtin_bit_cast(float, v);
}
__device__ inline float gelu_f(float x){ return 0.5f * x * (1.0f + erff(x * 0.70710678118654752440f)); }

// swizzled LDS store/load of 16B (8 bf16). stride must be a multiple of 128 bytes.
__device__ inline void sts16(char* lds, int row, int kb, int stride, bf16x8 v){
  *reinterpret_cast<bf16x8*>(lds + row*stride + (kb ^ ((row&7)<<4))) = v;
}
__device__ inline bf16x8 lds16(const char* lds, int row, int kb, int stride){
  return *reinterpret_cast<const bf16x8*>(lds + row*stride + (kb ^ ((row&7)<<4)));
}
__device__ inline void copyB(char* dst, const u16* src, int bytes, int tid, int nthr){
  for(int o = tid*16; o < bytes; o += nthr*16)
    *reinterpret_cast<bf16x8*>(dst + o) =
      *reinterpret_cast<const bf16x8*>(reinterpret_cast<const char*>(src) + o);
}

// MFMA core: one 16-row M-tile (mt) x NT 16-col tiles, K = KT*32, A/B both swizzled LDS.
template<int NT, int KT>
__device__ inline void mma_core(const char* sA, const char* sB, int strideA, int strideB,
                                f32x4* acc, int ln, int mt){
#pragma unroll
  for(int nt=0; nt<NT; ++nt) acc[nt] = f32x4{0.f,0.f,0.f,0.f};
#pragma unroll
  for(int kt=0; kt<KT; ++kt){
    int kb = kt*64 + ((ln>>4)<<4);
    bf16x8 a = lds16(sA, mt*16 + (ln&15), kb, strideA);
#pragma unroll
    for(int nt=0; nt<NT; ++nt){
      bf16x8 b = lds16(sB, nt*16 + (ln&15), kb, strideB);
      acc[nt] = __builtin_amdgcn_mfma_f32_16x16x32_bf16(a, b, acc[nt], 0, 0, 0);
    }
  }
}

// stage 64 rows x 64 cols (fp32 source) -> bf16 swizzled LDS, stride 128B
template<bool DOGELU>
__device__ inline void stageA_f32(char* sA, const float* src, int tid, int nthr){
  for(int s = tid; s < 512; s += nthr){
    int row = s >> 3, ks = s & 7;
    const float4* p = reinterpret_cast<const float4*>(src + row*64 + ks*8);
    float4 a = p[0], b = p[1];
    float f[8] = {a.x,a.y,a.z,a.w,b.x,b.y,b.z,b.w};
    if(DOGELU){
#pragma unroll
      for(int i=0;i<8;i++) f[i] = gelu_f(f[i]);
    }
    bf16x8 v;
#pragma unroll
    for(int i=0;i<8;i++) v[i] = (short)f2bf(f[i]);
    sts16(sA, row, ks*16, 128, v);
  }
}
template<bool DOGELU>
__device__ inline void stageA_bf16(char* sA, const u16* src, int tid, int nthr){
  for(int s = tid; s < 512; s += nthr){
    int row = s >> 3, ks = s & 7;
    bf16x8 v = *reinterpret_cast<const bf16x8*>(src + row*64 + ks*8);
    if(DOGELU){
#pragma unroll
      for(int i=0;i<8;i++) v[i] = (short)f2bf(gelu_f(bf2f(v[i])));
    }
    sts16(sA, row, ks*16, 128, v);
  }
}

// ---------- prep kernels ----------
__global__ void kzero(float* __restrict__ p, size_t n){
  for(size_t i = (size_t)blockIdx.x*256 + threadIdx.x; i < n; i += (size_t)gridDim.x*256) p[i] = 0.f;
}

// zero t1T pad nodes [370,384) for every (bt, c) — must run every call
__global__ void kzpad(u16* __restrict__ t1T){
  int idx = blockIdx.x*256 + threadIdx.x;   // 512*128 = 65536 (bt*128 + c)
  if(idx < BTOT*128){
    u16* d = t1T + (size_t)idx*384 + NN;
#pragma unroll
    for(int i=0;i<14;i++) d[i] = 0;
  }
}

__global__ void kbuildA(const int* __restrict__ ei, const float* __restrict__ ew, float* __restrict__ Araw, int E){
  int e = blockIdx.x*256 + threadIdx.x;
  if(e < E){
    int src = ei[e], dst = ei[E + e];
    atomicAdd(&Araw[dst*NN + src], ew[e]);
  }
}

__global__ __launch_bounds__(384) void knormF(float* __restrict__ Araw, float* __restrict__ dinvF){
  int i = threadIdx.x;
  if(i < NN){
    float d0 = Araw[i*NN+i];
    if(d0 == 0.f) Araw[i*NN+i] = 1.f;
    float s = 0.f;
    for(int j=0;j<NN;++j) s += Araw[i*NN+j];
    dinvF[i] = rsqrtf(s);
  }
}

// adaptive adjacency: one block per (row i, layer l); exact jax top_k tie-breaking
__global__ __launch_bounds__(384) void kadapt(const float* __restrict__ esrc, const float* __restrict__ etgt,
                                              float* __restrict__ ArawA, float* __restrict__ dinvA){
  __shared__ float tg[NN*16];
  __shared__ float sv[NN];
  __shared__ float red[8];
  int i = blockIdx.x, l = blockIdx.y, tid = threadIdx.x;
  const float* Et = etgt + (size_t)l*NN*16;
  for(int idx = tid; idx < NN*16; idx += 384) tg[idx] = Et[idx];
  float sr[16];
  const float* Es = esrc + ((size_t)l*NN + i)*16;
#pragma unroll
  for(int k=0;k<16;k++) sr[k] = Es[k];
  __syncthreads();
  bool act = tid < NN;
  float s = 0.f;
  if(act){
    float d = 0.f;
#pragma unroll
    for(int k=0;k<16;k++) d += sr[k]*tg[tid*16+k];
    s = fmaxf(d, 0.f);
  }
  // block max
  float v = act ? s : -1.f;
#pragma unroll
  for(int o=1;o<64;o<<=1) v = fmaxf(v, __shfl_xor(v,o,64));
  if((tid&63)==0) red[tid>>6] = v;
  __syncthreads();
  float mx = fmaxf(fmaxf(fmaxf(red[0],red[1]),fmaxf(red[2],red[3])),fmaxf(red[4],red[5]));
  __syncthreads();
  float e = act ? expf(s - mx) : 0.f;
  float t = e;
#pragma unroll
  for(int o=1;o<64;o<<=1) t += __shfl_xor(t,o,64);
  if((tid&63)==0) red[tid>>6] = t;
  __syncthreads();
  float sum = red[0]+red[1]+red[2]+red[3]+red[4]+red[5];
  float p = e / sum;
  if(act) sv[tid] = p;
  __syncthreads();
  float val = 0.f;
  if(act){
    int cnt = 0;
    for(int k=0;k<NN;++k){
      float pk = sv[k];
      cnt += ((pk > p) || (pk == p && k < tid)) ? 1 : 0;
    }
    val = (cnt < KTOPK) ? p : 0.f;
    if(tid == i && val == 0.f) val = 1.f;   // self-loop where diag missing
  }
  float dsum = val;
#pragma unroll
  for(int o=1;o<64;o<<=1) dsum += __shfl_xor(dsum,o,64);
  __syncthreads();
  if((tid&63)==0) red[tid>>6] = dsum;
  __syncthreads();
  float deg = red[0]+red[1]+red[2]+red[3]+red[4]+red[5];
  if(tid == 0) dinvA[l*NN + i] = rsqrtf(deg);
  if(act) ArawA[((size_t)l*NN + i)*NN + tid] = val;
}

// build normalized dense bf16 A_cat[l] = [A_fixed(384) | A_adapt(384)] over k=768
__global__ void kacat(const float* __restrict__ Araw, const float* __restrict__ ArawA,
                      const float* __restrict__ dinvF, const float* __restrict__ dinvA,
                      u16* __restrict__ Acat){
  int idx = blockIdx.x*256 + threadIdx.x;
  if(idx >= LL*384*768) return;
  int k = idx % 768; int m = (idx / 768) % 384; int l = idx / (768*384);
  float v = 0.f;
  if(m < NN){
    if(k < 384){
      if(k < NN) v = dinvF[m]*Araw[m*NN+k]*dinvF[k];
    } else {
      int n = k - 384;
      if(n < NN) v = dinvA[l*NN+m]*ArawA[((size_t)l*NN+m)*NN+n]*dinvA[l*NN+n];
    }
  }
  Acat[idx] = f2bf(v);
}

// pre-transposed + pre-swizzled weight tiles Bt[col][k]
__global__ void kbt_small(const float* __restrict__ inW, const float* __restrict__ e1W, const float* __restrict__ e2W,
                          u16* __restrict__ BtIN, u16* __restrict__ BtE1, u16* __restrict__ BtE2){
  const float* W = blockIdx.x==0 ? inW : (blockIdx.x==1 ? e1W : e2W);
  u16* Bt = blockIdx.x==0 ? BtIN : (blockIdx.x==1 ? BtE1 : BtE2);
  for(int idx = threadIdx.x; idx < 4096; idx += 256){
    int c = idx >> 6, k = idx & 63;
    *(u16*)((char*)Bt + c*128 + ((k*2) ^ ((c&7)<<4))) = f2bf(W[k*64 + c]);
  }
}

__global__ void kbt_layer(const float* __restrict__ gcnfW, const float* __restrict__ gcnaW,
                          const float* __restrict__ filtW, const float* __restrict__ gateW,
                          const float* __restrict__ skipW, const float* __restrict__ resW,
                          u16* __restrict__ BtUV, u16* __restrict__ BtCV, u16* __restrict__ BtSR){
  int l = blockIdx.x, which = blockIdx.y;
  if(which == 0){            // [Wf | Wa] : 128 cols x 64 k
    u16* Bt = BtUV + (size_t)l*128*64;
    for(int idx=threadIdx.x; idx<8192; idx+=256){
      int c = idx>>6, k = idx&63;
      float v = (c<64) ? gcnfW[(size_t)l*4096 + k*64 + c] : gcnaW[(size_t)l*4096 + k*64 + (c-64)];
      *(u16*)((char*)Bt + c*128 + ((k*2) ^ ((c&7)<<4))) = f2bf(v);
    }
  } else if(which == 1){     // conv [filt | gate] : 128 cols x 128 k (k<64: cur tap1, k>=64: prev tap0)
    u16* Bt = BtCV + (size_t)l*128*128;
    for(int idx=threadIdx.x; idx<16384; idx+=256){
      int c = idx>>7, k = idx&127;
      const float* W = (c<64) ? filtW : gateW;
      int o = c & 63, ii = k & 63, tap = (k<64) ? 1 : 0;
      float v = W[(size_t)l*8192 + o*128 + ii*2 + tap];
      *(u16*)((char*)Bt + c*256 + ((k*2) ^ ((c&7)<<4))) = f2bf(v);
    }
  } else {                   // [skip | res] : 128 cols x 64 k
    u16* Bt = BtSR + (size_t)l*128*64;
    for(int idx=threadIdx.x; idx<8192; idx+=256){
      int c = idx>>6, k = idx&63;
      float v = (c<64) ? skipW[(size_t)l*4096 + c*64 + k] : resW[(size_t)l*4096 + (c-64)*64 + k];
      *(u16*)((char*)Bt + c*128 + ((k*2) ^ ((c&7)<<4))) = f2bf(v);
    }
  }
}

// eeg1_W (23680x256 fp32) -> Wt (256 x 23680 bf16)
__global__ void ktrans(const float* __restrict__ W, u16* __restrict__ Wt){
  __shared__ float tile[64][65];
  int kb = blockIdx.x*64, cb = blockIdx.y*64;
  for(int idx = threadIdx.x; idx < 4096; idx += 256){
    int kk = idx>>6, cc = idx&63;
    tile[kk][cc] = W[(size_t)(kb+kk)*256 + cb+cc];
  }
  __syncthreads();
  for(int idx = threadIdx.x; idx < 4096; idx += 256){
    int cc = idx>>6, kk = idx&63;
    Wt[(size_t)(cb+cc)*23680 + kb+kk] = f2bf(tile[kk][cc]);
  }
}

// ---------- main pipeline kernels ----------
__global__ __launch_bounds__(256) void krowmm_in(const float* __restrict__ X, const u16* __restrict__ Bt,
                                                 const float* __restrict__ bias, float* __restrict__ out){
  __shared__ char sA[8192];
  __shared__ char sB[8192];
  int tid = threadIdx.x;
  copyB(sB, Bt, 8192, tid, 256);
  stageA_f32<false>(sA, X + (size_t)blockIdx.x*4096, tid, 256);
  __syncthreads();
  int w = tid>>6, ln = tid&63;
  f32x4 acc[4];
  mma_core<4,2>(sA, sB, 128, 128, acc, ln, w);
  size_t rbase = (size_t)blockIdx.x*64 + w*16 + ((ln>>4)<<2);
#pragma unroll
  for(int nt=0; nt<4; ++nt){
    int c = nt*16 + (ln&15);
    float bv = bias[c];
#pragma unroll
    for(int r=0;r<4;++r) out[(rbase+r)*64 + c] = acc[nt][r] + bv;
  }
}

// grid (6, BTOT): block = 64 node-rows of one bt. Writes t1T[bt][c=128][node pad 384].
__global__ __launch_bounds__(256) void krowmm_uv(const float* __restrict__ X, const u16* __restrict__ Bt,
                                                 u16* __restrict__ t1T){
  __shared__ char sA[8192];
  __shared__ char sB[16384];
  int nb = blockIdx.x, bt = blockIdx.y, tid = threadIdx.x;
  copyB(sB, Bt, 16384, tid, 256);
  int rows_valid = NN - nb*64; if(rows_valid > 64) rows_valid = 64;
  const float* src = X + ((size_t)bt*NN + nb*64)*64;
  for(int s = tid; s < 512; s += 256){
    int row = s >> 3, ks = s & 7;
    bf16x8 v;
    if(row < rows_valid){
      const float4* p4 = reinterpret_cast<const float4*>(src + row*64 + ks*8);
      float4 a = p4[0], b = p4[1];
      float f[8] = {a.x,a.y,a.z,a.w,b.x,b.y,b.z,b.w};
#pragma unroll
      for(int i=0;i<8;i++) v[i] = (short)f2bf(f[i]);
    } else {
      bf16x8 z = {0,0,0,0,0,0,0,0}; v = z;
    }
    sts16(sA, row, ks*16, 128, v);
  }
  __syncthreads();
  int w = tid>>6, ln = tid&63;
  f32x4 acc[8];
  mma_core<8,2>(sA, sB, 128, 128, acc, ln, w);
  int nd0 = nb*64 + w*16 + ((ln>>4)<<2);        // node base of this 4-row fragment (mult of 4)
  u16* dstb = t1T + (size_t)bt*T1TSTRIDE;
  if(nd0 + 3 < NN){
#pragma unroll
    for(int nt=0; nt<8; ++nt){
      int c = nt*16 + (ln&15);
      s16x4 v;
#pragma unroll
      for(int r=0;r<4;++r) v[r] = (short)f2bf(acc[nt][r]);
      *reinterpret_cast<s16x4*>(dstb + (size_t)c*384 + nd0) = v;
    }
  } else if(nd0 < NN){
#pragma unroll
    for(int nt=0; nt<8; ++nt){
      int c = nt*16 + (ln&15);
#pragma unroll
      for(int r=0;r<4;++r)
        if(nd0 + r < NN) dstb[(size_t)c*384 + nd0 + r] = f2bf(acc[nt][r]);
    }
  }
}

// per-(b,t): OUT(370x64) = A_cat(384x768) @ W_big(768x64), + (gcnf_b + gcna_b)
// W_big rows: k<384 -> U = t1T rows c in [0,64); k>=384 -> V = t1T rows c in [64,128)
__global__ __launch_bounds__(512) void kspmm(const u16* __restrict__ t1T, const u16* __restrict__ Acat,
                                             const float* __restrict__ bfb, const float* __restrict__ bab,
                                             u16* __restrict__ t2){
  __shared__ char uvt[64*768];   // 48KB: one phase of W_big^T [n=64][k=384]
  int bt = blockIdx.x, tid = threadIdx.x;
  int w = tid>>6, ln = tid&63;
  f32x4 acc[12];
#pragma unroll
  for(int j=0;j<12;j++) acc[j] = f32x4{0.f,0.f,0.f,0.f};
  const char* srcb = (const char*)(t1T + (size_t)bt*T1TSTRIDE);
  int srow = tid >> 3, sk0 = (tid & 7) << 4;
  int kboff = (ln>>4)<<4;
  int lr = ln & 15;
  for(int p=0; p<2; ++p){
    __syncthreads();
#pragma unroll
    for(int j=0;j<6;++j){
      int kb = sk0 + j*128;
      bf16x8 v = *reinterpret_cast<const bf16x8*>(srcb + (size_t)(p*64 + srow)*768 + kb);
      sts16(uvt, srow, kb, 768, v);
    }
    __syncthreads();
    const char* abase = (const char*)Acat + p*768 + kboff;
#pragma unroll
    for(int kt=0; kt<12; ++kt){
      bf16x8 a0 = *reinterpret_cast<const bf16x8*>(abase + (size_t)((w*3+0)*16 + lr)*1536 + kt*64);
      bf16x8 a1 = *reinterpret_cast<const bf16x8*>(abase + (size_t)((w*3+1)*16 + lr)*1536 + kt*64);
      bf16x8 a2 = *reinterpret_cast<const bf16x8*>(abase + (size_t)((w*3+2)*16 + lr)*1536 + kt*64);
      bf16x8 b0 = lds16(uvt, 0*16 + lr, kt*64 + kboff, 768);
      bf16x8 b1 = lds16(uvt, 1*16 + lr, kt*64 + kboff, 768);
      bf16x8 b2 = lds16(uvt, 2*16 + lr, kt*64 + kboff, 768);
      bf16x8 b3 = lds16(uvt, 3*16 + lr, kt*64 + kboff, 768);
      acc[0]  = __builtin_amdgcn_mfma_f32_16x16x32_bf16(a0, b0, acc[0],  0,0,0);
      acc[1]  = __builtin_amdgcn_mfma_f32_16x16x32_bf16(a0, b1, acc[1],  0,0,0);
      acc[2]  = __builtin_amdgcn_mfma_f32_16x16x32_bf16(a0, b2, acc[2],  0,0,0);
      acc[3]  = __builtin_amdgcn_mfma_f32_16x16x32_bf16(a0, b3, acc[3],  0,0,0);
      acc[4]  = __builtin_amdgcn_mfma_f32_16x16x32_bf16(a1, b0, acc[4],  0,0,0);
      acc[5]  = __builtin_amdgcn_mfma_f32_16x16x32_bf16(a1, b1, acc[5],  0,0,0);
      acc[6]  = __builtin_amdgcn_mfma_f32_16x16x32_bf16(a1, b2, acc[6],  0,0,0);
      acc[7]  = __builtin_amdgcn_mfma_f32_16x16x32_bf16(a1, b3, acc[7],  0,0,0);
      acc[8]  = __builtin_amdgcn_mfma_f32_16x16x32_bf16(a2, b0, acc[8],  0,0,0);
      acc[9]  = __builtin_amdgcn_mfma_f32_16x16x32_bf16(a2, b1, acc[9],  0,0,0);
      acc[10] = __builtin_amdgcn_mfma_f32_16x16x32_bf16(a2, b2, acc[10], 0,0,0);
      acc[11] = __builtin_amdgcn_mfma_f32_16x16x32_bf16(a2, b3, acc[11], 0,0,0);
    }
  }
#pragma unroll
  for(int mi=0; mi<3; ++mi){
    int mt = w*3 + mi;
    int mbase = mt*16 + ((ln>>4)<<2);
#pragma unroll
    for(int nt=0; nt<4; ++nt){
      int col = nt*16 + lr;
      float bias = bfb[col] + bab[col];
#pragma unroll
      for(int r=0;r<4;++r){
        int m = mbase + r;
        if(m < NN) t2[((size_t)bt*NN + m)*64 + col] = f2bf(acc[mi*4+nt][r] + bias);
      }
    }
  }
}

// gated causal conv: out = tanh(filt)*sigmoid(gate); A rows = [h(t) ; h(t-dil)]
__global__ __launch_bounds__(256) void kconv(const u16* __restrict__ t2, const u16* __restrict__ Bt,
                                             const float* __restrict__ fb, const float* __restrict__ gb,
                                             u16* __restrict__ t3, int dil){
  __shared__ char sA[64*256];    // 16KB
  __shared__ char sB[128*256];   // 32KB
  int blk = blockIdx.x, tid = threadIdx.x;
  copyB(sB, Bt, 32768, tid, 256);
  int r0 = blk*64;
  for(int s = tid; s < 1024; s += 256){
    int row = s >> 4, sc = s & 15;
    int r = r0 + row;
    bf16x8 v;
    if(sc < 8){
      v = *reinterpret_cast<const bf16x8*>(t2 + (size_t)r*64 + sc*8);
    } else {
      int t = (r / NN) % TT;
      if(t >= dil) v = *reinterpret_cast<const bf16x8*>(t2 + (size_t)(r - dil*NN)*64 + (sc-8)*8);
      else { bf16x8 z = {0,0,0,0,0,0,0,0}; v = z; }
    }
    sts16(sA, row, sc*16, 256, v);
  }
  __syncthreads();
  int w = tid>>6, ln = tid&63;
  f32x4 acc[8];
  mma_core<8,4>(sA, sB, 256, 256, acc, ln, w);
  size_t rbase = (size_t)r0 + w*16 + ((ln>>4)<<2);
#pragma unroll
  for(int nt=0; nt<4; ++nt){
    int o = nt*16 + (ln&15);
    float fbv = fb[o], gbv = gb[o];
#pragma unroll
    for(int r=0;r<4;++r){
      float fv = acc[nt][r] + fbv;
      float gv = acc[nt+4][r] + gbv;
      float ov = tanhf(fv) * (1.f/(1.f + expf(-gv)));
      t3[(rbase+r)*64 + o] = f2bf(ov);
    }
  }
}

// fused skip/res 1x1 convs + residual + LayerNorm + skip accumulation (skip in bf16)
__global__ __launch_bounds__(256) void ksr(const u16* __restrict__ t3, const u16* __restrict__ Bt,
                                           const float* __restrict__ sb, const float* __restrict__ rb,
                                           const float* __restrict__ lng, const float* __restrict__ lnb,
                                           float* __restrict__ xbuf, u16* __restrict__ skip, int first){
  __shared__ char sA[8192];
  __shared__ char sB[16384];
  __shared__ float stg[64][128];
  int tid = threadIdx.x;
  copyB(sB, Bt, 16384, tid, 256);
  stageA_bf16<false>(sA, t3 + (size_t)blockIdx.x*4096, tid, 256);
  __syncthreads();
  int w = tid>>6, ln = tid&63;
  f32x4 acc[8];
  mma_core<8,2>(sA, sB, 128, 128, acc, ln, w);
  int lrbase = w*16 + ((ln>>4)<<2);
#pragma unroll
  for(int nt=0; nt<8; ++nt){
    int c = nt*16 + (ln&15);
#pragma unroll
    for(int r=0;r<4;++r) stg[lrbase+r][c] = acc[nt][r];
  }
  __syncthreads();
  size_t r0 = (size_t)blockIdx.x*64;
  for(int rr=0; rr<16; ++rr){
    int lrow = w*16 + rr;
    size_t gi = (r0 + lrow)*64 + ln;
    float s  = stg[lrow][ln]    + sb[ln];
    float re = stg[lrow][64+ln] + rb[ln];
    float y = re + xbuf[gi];
    float t = y;
#pragma unroll
    for(int o=1;o<64;o<<=1) t += __shfl_xor(t, o, 64);
    float m = t * (1.f/64.f);
    float d = y - m;
    float q = d*d;
#pragma unroll
    for(int o=1;o<64;o<<=1) q += __shfl_xor(q, o, 64);
    float vv = q * (1.f/64.f);
    float xo = d * rsqrtf(vv + 1e-5f) * lng[ln] + lnb[ln];
    xbuf[gi] = xo;
    if(first) skip[gi] = f2bf(s);
    else      skip[gi] = f2bf(bf2f((short)skip[gi]) + s);
  }
}

__global__ __launch_bounds__(256) void kend_bf16(const u16* __restrict__ X, const u16* __restrict__ Bt,
                                                 const float* __restrict__ bias, u16* __restrict__ out){
  __shared__ char sA[8192];
  __shared__ char sB[8192];
  int tid = threadIdx.x;
  copyB(sB, Bt, 8192, tid, 256);
  stageA_bf16<true>(sA, X + (size_t)blockIdx.x*4096, tid, 256);
  __syncthreads();
  int w = tid>>6, ln = tid&63;
  f32x4 acc[4];
  mma_core<4,2>(sA, sB, 128, 128, acc, ln, w);
  size_t rbase = (size_t)blockIdx.x*64 + w*16 + ((ln>>4)<<2);
#pragma unroll
  for(int nt=0; nt<4; ++nt){
    int c = nt*16 + (ln&15);
    float bv = bias[c];
#pragma unroll
    for(int r=0;r<4;++r) out[(rbase+r)*64 + c] = f2bf(acc[nt][r] + bv);
  }
}

// eeg1: (512 x 23680) @ (23680 x 256), split-K partials (deterministic, no atomics)
__global__ __launch_bounds__(512) void keeg1(const u16* __restrict__ h2, const u16* __restrict__ WtE,
                                             float* __restrict__ part){
  __shared__ char sA[64*128];    // 8KB
  __shared__ char sB[256*128];   // 32KB
  int rowg = blockIdx.x, sp = blockIdx.y;
  int tid = threadIdx.x, w = tid>>6, ln = tid&63;
  f32x4 acc[8];
#pragma unroll
  for(int i=0;i<8;i++) acc[i] = f32x4{0.f,0.f,0.f,0.f};
  int mt = w & 3, ntb = (w>>2)*8;
  for(int ks=0; ks<74; ++ks){
    int k0 = (sp*74 + ks)*32;
    __syncthreads();
    for(int s = tid; s < 256; s += 512){
      int row = s>>2, kc = s&3;
      bf16x8 v = *reinterpret_cast<const bf16x8*>(h2 + (size_t)(rowg*64+row)*23680 + k0 + kc*8);
      sts16(sA, row, kc*16, 128, v);
    }
    for(int s = tid; s < 1024; s += 512){
      int row = s>>2, kc = s&3;
      bf16x8 v = *reinterpret_cast<const bf16x8*>(WtE + (size_t)row*23680 + k0 + kc*8);
      sts16(sB, row, kc*16, 128, v);
    }
    __syncthreads();
    bf16x8 a = lds16(sA, mt*16 + (ln&15), ((ln>>4)<<4), 128);
#pragma unroll
    for(int j=0;j<8;++j){
      bf16x8 b = lds16(sB, (ntb+j)*16 + (ln&15), ((ln>>4)<<4), 128);
      acc[j] = __builtin_amdgcn_mfma_f32_16x16x32_bf16(a, b, acc[j], 0, 0, 0);
    }
  }
  float* dst = part + ((size_t)sp*512 + rowg*64)*256;
#pragma unroll
  for(int j=0;j<8;++j){
    int c = (ntb+j)*16 + (ln&15);
#pragma unroll
    for(int r=0;r<4;++r){
      int row = mt*16 + ((ln>>4)<<2) + r;
      dst[(size_t)row*256 + c] = acc[j][r];
    }
  }
}

// reduce partials + bias + gelu, then @ eeg2_W + b2 -> output (fp32)
__global__ __launch_bounds__(256) void keeg2(const float* __restrict__ part, const float* __restrict__ b1,
                                             const float* __restrict__ W2, const float* __restrict__ b2,
                                             float* __restrict__ out){
  __shared__ float u[256];
  __shared__ float pr[4][64];
  int bt = blockIdx.x, tid = threadIdx.x;
  float sacc = 0.f;
  for(int sp2=0; sp2<SPLITK; ++sp2) sacc += part[((size_t)sp2*512 + bt)*256 + tid];
  u[tid] = gelu_f(sacc + b1[tid]);
  __syncthreads();
  int w = tid>>6, ln = tid&63;
  float acc = 0.f;
  for(int c = w*64; c < (w+1)*64; ++c) acc += u[c] * W2[c*64 + ln];
  pr[w][ln] = acc;
  __syncthreads();
  if(tid < 64)
    out[(size_t)bt*64 + tid] = pr[0][tid]+pr[1][tid]+pr[2][tid]+pr[3][tid] + b2[tid];
}

// ---------- launcher ----------
extern "C" void kernel_launch(void* const* d_in, const int* in_sizes, int n_in,
                              void* d_out, int out_size, void* d_ws, size_t ws_size,
                              hipStream_t stream){
  const float* x_in  = (const float*)d_in[0];
  const int*   ei    = (const int*)d_in[1];
  const float* ew    = (const float*)d_in[2];
  const float* in_W  = (const float*)d_in[3];
  const float* in_b  = (const float*)d_in[4];
  const float* gcnfW = (const float*)d_in[5];
  const float* gcnfb = (const float*)d_in[6];
  const float* esrc  = (const float*)d_in[7];
  const float* etgt  = (const float*)d_in[8];
  const float* gcnaW = (const float*)d_in[9];
  const float* gcnab = (const float*)d_in[10];
  const float* filtW = (const float*)d_in[11];
  const float* filtb = (const float*)d_in[12];
  const float* gateW = (const float*)d_in[13];
  const float* gateb = (const float*)d_in[14];
  const float* resW  = (const float*)d_in[15];
  const float* resb  = (const float*)d_in[16];
  const float* skipW = (const float*)d_in[17];
  const float* skipb = (const float*)d_in[18];
  const float* lng   = (const float*)d_in[19];
  const float* lnb   = (const float*)d_in[20];
  const float* e1W   = (const float*)d_in[21];
  const float* e1b   = (const float*)d_in[22];
  const float* e2W   = (const float*)d_in[23];
  const float* e2b   = (const float*)d_in[24];
  const float* eg1W  = (const float*)d_in[25];
  const float* eg1b  = (const float*)d_in[26];
  const float* eg2W  = (const float*)d_in[27];
  const float* eg2b  = (const float*)d_in[28];
  int E = in_sizes[2];

  char* p = (char*)d_ws;
  auto carve = [&](size_t bytes)->char*{ char* r = p; p += (bytes + 255) & ~(size_t)255; return r; };
  float* xbuf  = (float*)carve((size_t)RR*64*4);
  u16*   skip  = (u16*)  carve((size_t)RR*64*2);
  u16*   t1T   = (u16*)  carve((size_t)BTOT*T1TSTRIDE*2);   // [bt][128][384]
  u16*   t2    = (u16*)  carve((size_t)RR*64*2);
  u16*   t3    = (u16*)  carve((size_t)RR*64*2);
  float* Araw9 = (float*)carve((size_t)9*NN*NN*4);   // [fixed | 8 adaptive raw]
  float* Araw  = Araw9;
  float* ArawA = Araw9 + (size_t)NN*NN;
  float* dinvF = (float*)carve(NN*4);
  float* dinvA = (float*)carve(LL*NN*4);
  u16*   Acat  = (u16*)  carve((size_t)LL*384*768*2);
  u16*   BtUV  = (u16*)  carve((size_t)LL*128*64*2);
  u16*   BtCV  = (u16*)  carve((size_t)LL*128*128*2);
  u16*   BtSR  = (u16*)  carve((size_t)LL*128*64*2);
  u16*   BtIN  = (u16*)  carve(64*64*2);
  u16*   BtE1  = (u16*)  carve(64*64*2);
  u16*   BtE2  = (u16*)  carve(64*64*2);
  u16*   WtE   = (u16*)  carve((size_t)256*23680*2);
  float* part  = (float*)carve((size_t)SPLITK*512*256*4);
  u16* h1 = t1T;                      // overlay: t1T unused after layer loop
  u16* h2 = t1T + (size_t)RR*64;      // fits: BTOT*T1TSTRIDE = 25.2M elems >= 2*RR*64 = 24.2M

  // --- prep ---
  kzero<<<1024, 256, 0, stream>>>(Araw9, (size_t)9*NN*NN);
  kzpad<<<(BTOT*128 + 255)/256, 256, 0, stream>>>(t1T);
  kbuildA<<<(E+255)/256, 256, 0, stream>>>(ei, ew, Araw, E);
  knormF<<<1, 384, 0, stream>>>(Araw, dinvF);
  kadapt<<<dim3(NN, LL), 384, 0, stream>>>(esrc, etgt, ArawA, dinvA);
  kacat<<<(LL*384*768 + 255)/256, 256, 0, stream>>>(Araw, ArawA, dinvF, dinvA, Acat);
  kbt_small<<<3, 256, 0, stream>>>(in_W, e1W, e2W, BtIN, BtE1, BtE2);
  kbt_layer<<<dim3(LL, 3), 256, 0, stream>>>(gcnfW, gcnaW, filtW, gateW, skipW, resW, BtUV, BtCV, BtSR);
  ktrans<<<dim3(370, 4), 256, 0, stream>>>(eg1W, WtE);

  // --- input proj ---
  krowmm_in<<<RR/64, 256, 0, stream>>>(x_in, BtIN, in_b, xbuf);

  // --- layers ---
  for(int l=0; l<LL; ++l){
    int dil = 1 << (l & 3);
    krowmm_uv<<<dim3(6, BTOT), 256, 0, stream>>>(xbuf, BtUV + (size_t)l*8192, t1T);
    kspmm<<<BTOT, 512, 0, stream>>>(t1T, Acat + (size_t)l*384*768, gcnfb + l*64, gcnab + l*64, t2);
    kconv<<<RR/64, 256, 0, stream>>>(t2, BtCV + (size_t)l*16384, filtb + l*64, gateb + l*64, t3, dil);
    ksr<<<RR/64, 256, 0, stream>>>(t3, BtSR + (size_t)l*8192, skipb + l*64, resb + l*64,
                                   lng + l*64, lnb + l*64, xbuf, skip, l==0 ? 1 : 0);
  }

  // --- tail ---
  kend_bf16<<<RR/64, 256, 0, stream>>>(skip, BtE1, e1b, h1);
  kend_bf16<<<RR/64, 256, 0, stream>>>(h1, BtE2, e2b, h2);
  keeg1<<<dim3(8, SPLITK), 512, 0, stream>>>(h2, WtE, part);
  keeg2<<<BTOT, 256, 0, stream>>>(part, eg1b, eg2W, eg2b, (float*)d_out);
}

// Round 3
// 1416.098 us; speedup vs baseline: 1.8281x; 1.4451x over previous
//
#include <hip/hip_runtime.h>
#include <hip/hip_bf16.h>
#include <math.h>

typedef __attribute__((ext_vector_type(8))) short bf16x8;
typedef __attribute__((ext_vector_type(4))) short s16x4;
typedef __attribute__((ext_vector_type(4))) float f32x4;
typedef unsigned short u16;
typedef unsigned int u32;

#define NN 370
#define HH 64
#define LL 8
#define TT 64
#define BTOT 512            // B*T
#define RR (BTOT*NN)        // 189440 rows
#define KTOPK 37
#define SPLITK 10
#define T1TSTRIDE 49152     // 128*384 elements per bt in t1T

// ---------- helpers ----------
__device__ inline u16 f2bf(float f){
  __hip_bfloat16 h = __float2bfloat16(f);
  return __builtin_bit_cast(u16, h);
}
__device__ inline float bf2f(short s){
  u32 v = ((u32)(u16)s) << 16;
  return __builtin_bit_cast(float, v);
}
__device__ inline float gelu_f(float x){ return 0.5f * x * (1.0f + erff(x * 0.70710678118654752440f)); }

// swizzled LDS store/load of 16B (8 bf16). stride must be a multiple of 128 bytes.
__device__ inline void sts16(char* lds, int row, int kb, int stride, bf16x8 v){
  *reinterpret_cast<bf16x8*>(lds + row*stride + (kb ^ ((row&7)<<4))) = v;
}
__device__ inline bf16x8 lds16(const char* lds, int row, int kb, int stride){
  return *reinterpret_cast<const bf16x8*>(lds + row*stride + (kb ^ ((row&7)<<4)));
}
__device__ inline void copyB(char* dst, const u16* src, int bytes, int tid, int nthr){
  for(int o = tid*16; o < bytes; o += nthr*16)
    *reinterpret_cast<bf16x8*>(dst + o) =
      *reinterpret_cast<const bf16x8*>(reinterpret_cast<const char*>(src) + o);
}

// MFMA core: one 16-row M-tile (mt) x NT 16-col tiles, K = KT*32, A/B both swizzled LDS.
template<int NT, int KT>
__device__ inline void mma_core(const char* sA, const char* sB, int strideA, int strideB,
                                f32x4* acc, int ln, int mt){
#pragma unroll
  for(int nt=0; nt<NT; ++nt) acc[nt] = f32x4{0.f,0.f,0.f,0.f};
#pragma unroll
  for(int kt=0; kt<KT; ++kt){
    int kb = kt*64 + ((ln>>4)<<4);
    bf16x8 a = lds16(sA, mt*16 + (ln&15), kb, strideA);
#pragma unroll
    for(int nt=0; nt<NT; ++nt){
      bf16x8 b = lds16(sB, nt*16 + (ln&15), kb, strideB);
      acc[nt] = __builtin_amdgcn_mfma_f32_16x16x32_bf16(a, b, acc[nt], 0, 0, 0);
    }
  }
}

// stage 64 rows x 64 cols (fp32 source) -> bf16 swizzled LDS, stride 128B
template<bool DOGELU>
__device__ inline void stageA_f32(char* sA, const float* src, int tid, int nthr){
  for(int s = tid; s < 512; s += nthr){
    int row = s >> 3, ks = s & 7;
    const float4* p = reinterpret_cast<const float4*>(src + row*64 + ks*8);
    float4 a = p[0], b = p[1];
    float f[8] = {a.x,a.y,a.z,a.w,b.x,b.y,b.z,b.w};
    if(DOGELU){
#pragma unroll
      for(int i=0;i<8;i++) f[i] = gelu_f(f[i]);
    }
    bf16x8 v;
#pragma unroll
    for(int i=0;i<8;i++) v[i] = (short)f2bf(f[i]);
    sts16(sA, row, ks*16, 128, v);
  }
}
template<bool DOGELU>
__device__ inline void stageA_bf16(char* sA, const u16* src, int tid, int nthr){
  for(int s = tid; s < 512; s += nthr){
    int row = s >> 3, ks = s & 7;
    bf16x8 v = *reinterpret_cast<const bf16x8*>(src + row*64 + ks*8);
    if(DOGELU){
#pragma unroll
      for(int i=0;i<8;i++) v[i] = (short)f2bf(gelu_f(bf2f(v[i])));
    }
    sts16(sA, row, ks*16, 128, v);
  }
}

// ---------- prep kernels ----------
__global__ void kzero(float* __restrict__ p, size_t n){
  for(size_t i = (size_t)blockIdx.x*256 + threadIdx.x; i < n; i += (size_t)gridDim.x*256) p[i] = 0.f;
}

// zero t1T pad nodes [370,384) for every (bt, c) — must run every call
__global__ void kzpad(u16* __restrict__ t1T){
  int idx = blockIdx.x*256 + threadIdx.x;   // 512*128 = 65536 (bt*128 + c)
  if(idx < BTOT*128){
    u16* d = t1T + (size_t)idx*384 + NN;
#pragma unroll
    for(int i=0;i<14;i++) d[i] = 0;
  }
}

__global__ void kbuildA(const int* __restrict__ ei, const float* __restrict__ ew, float* __restrict__ Araw, int E){
  int e = blockIdx.x*256 + threadIdx.x;
  if(e < E){
    int src = ei[e], dst = ei[E + e];
    atomicAdd(&Araw[dst*NN + src], ew[e]);
  }
}

__global__ __launch_bounds__(384) void knormF(float* __restrict__ Araw, float* __restrict__ dinvF){
  int i = threadIdx.x;
  if(i < NN){
    float d0 = Araw[i*NN+i];
    if(d0 == 0.f) Araw[i*NN+i] = 1.f;
    float s = 0.f;
    for(int j=0;j<NN;++j) s += Araw[i*NN+j];
    dinvF[i] = rsqrtf(s);
  }
}

// adaptive adjacency: one block per (row i, layer l); exact jax top_k tie-breaking
__global__ __launch_bounds__(384) void kadapt(const float* __restrict__ esrc, const float* __restrict__ etgt,
                                              float* __restrict__ ArawA, float* __restrict__ dinvA){
  __shared__ float tg[NN*16];
  __shared__ float sv[NN];
  __shared__ float red[8];
  int i = blockIdx.x, l = blockIdx.y, tid = threadIdx.x;
  const float* Et = etgt + (size_t)l*NN*16;
  for(int idx = tid; idx < NN*16; idx += 384) tg[idx] = Et[idx];
  float sr[16];
  const float* Es = esrc + ((size_t)l*NN + i)*16;
#pragma unroll
  for(int k=0;k<16;k++) sr[k] = Es[k];
  __syncthreads();
  bool act = tid < NN;
  float s = 0.f;
  if(act){
    float d = 0.f;
#pragma unroll
    for(int k=0;k<16;k++) d += sr[k]*tg[tid*16+k];
    s = fmaxf(d, 0.f);
  }
  // block max
  float v = act ? s : -1.f;
#pragma unroll
  for(int o=1;o<64;o<<=1) v = fmaxf(v, __shfl_xor(v,o,64));
  if((tid&63)==0) red[tid>>6] = v;
  __syncthreads();
  float mx = fmaxf(fmaxf(fmaxf(red[0],red[1]),fmaxf(red[2],red[3])),fmaxf(red[4],red[5]));
  __syncthreads();
  float e = act ? expf(s - mx) : 0.f;
  float t = e;
#pragma unroll
  for(int o=1;o<64;o<<=1) t += __shfl_xor(t,o,64);
  if((tid&63)==0) red[tid>>6] = t;
  __syncthreads();
  float sum = red[0]+red[1]+red[2]+red[3]+red[4]+red[5];
  float p = e / sum;
  if(act) sv[tid] = p;
  __syncthreads();
  float val = 0.f;
  if(act){
    int cnt = 0;
    for(int k=0;k<NN;++k){
      float pk = sv[k];
      cnt += ((pk > p) || (pk == p && k < tid)) ? 1 : 0;
    }
    val = (cnt < KTOPK) ? p : 0.f;
    if(tid == i && val == 0.f) val = 1.f;   // self-loop where diag missing
  }
  float dsum = val;
#pragma unroll
  for(int o=1;o<64;o<<=1) dsum += __shfl_xor(dsum,o,64);
  __syncthreads();
  if((tid&63)==0) red[tid>>6] = dsum;
  __syncthreads();
  float deg = red[0]+red[1]+red[2]+red[3]+red[4]+red[5];
  if(tid == 0) dinvA[l*NN + i] = rsqrtf(deg);
  if(act) ArawA[((size_t)l*NN + i)*NN + tid] = val;
}

// build normalized dense bf16 A_cat[l] = [A_fixed(384) | A_adapt(384)] over k=768
__global__ void kacat(const float* __restrict__ Araw, const float* __restrict__ ArawA,
                      const float* __restrict__ dinvF, const float* __restrict__ dinvA,
                      u16* __restrict__ Acat){
  int idx = blockIdx.x*256 + threadIdx.x;
  if(idx >= LL*384*768) return;
  int k = idx % 768; int m = (idx / 768) % 384; int l = idx / (768*384);
  float v = 0.f;
  if(m < NN){
    if(k < 384){
      if(k < NN) v = dinvF[m]*Araw[m*NN+k]*dinvF[k];
    } else {
      int n = k - 384;
      if(n < NN) v = dinvA[l*NN+m]*ArawA[((size_t)l*NN+m)*NN+n]*dinvA[l*NN+n];
    }
  }
  Acat[idx] = f2bf(v);
}

// pre-transposed + pre-swizzled weight tiles Bt[col][k]
__global__ void kbt_small(const float* __restrict__ inW, const float* __restrict__ e1W, const float* __restrict__ e2W,
                          u16* __restrict__ BtIN, u16* __restrict__ BtE1, u16* __restrict__ BtE2){
  const float* W = blockIdx.x==0 ? inW : (blockIdx.x==1 ? e1W : e2W);
  u16* Bt = blockIdx.x==0 ? BtIN : (blockIdx.x==1 ? BtE1 : BtE2);
  for(int idx = threadIdx.x; idx < 4096; idx += 256){
    int c = idx >> 6, k = idx & 63;
    *(u16*)((char*)Bt + c*128 + ((k*2) ^ ((c&7)<<4))) = f2bf(W[k*64 + c]);
  }
}

__global__ void kbt_layer(const float* __restrict__ gcnfW, const float* __restrict__ gcnaW,
                          const float* __restrict__ filtW, const float* __restrict__ gateW,
                          const float* __restrict__ skipW, const float* __restrict__ resW,
                          u16* __restrict__ BtUV, u16* __restrict__ BtCV, u16* __restrict__ BtSR){
  int l = blockIdx.x, which = blockIdx.y;
  if(which == 0){            // [Wf | Wa] : 128 cols x 64 k
    u16* Bt = BtUV + (size_t)l*128*64;
    for(int idx=threadIdx.x; idx<8192; idx+=256){
      int c = idx>>6, k = idx&63;
      float v = (c<64) ? gcnfW[(size_t)l*4096 + k*64 + c] : gcnaW[(size_t)l*4096 + k*64 + (c-64)];
      *(u16*)((char*)Bt + c*128 + ((k*2) ^ ((c&7)<<4))) = f2bf(v);
    }
  } else if(which == 1){     // conv [filt | gate] : 128 cols x 128 k (k<64: cur tap1, k>=64: prev tap0)
    u16* Bt = BtCV + (size_t)l*128*128;
    for(int idx=threadIdx.x; idx<16384; idx+=256){
      int c = idx>>7, k = idx&127;
      const float* W = (c<64) ? filtW : gateW;
      int o = c & 63, ii = k & 63, tap = (k<64) ? 1 : 0;
      float v = W[(size_t)l*8192 + o*128 + ii*2 + tap];
      *(u16*)((char*)Bt + c*256 + ((k*2) ^ ((c&7)<<4))) = f2bf(v);
    }
  } else {                   // [skip | res] : 128 cols x 64 k
    u16* Bt = BtSR + (size_t)l*128*64;
    for(int idx=threadIdx.x; idx<8192; idx+=256){
      int c = idx>>6, k = idx&63;
      float v = (c<64) ? skipW[(size_t)l*4096 + c*64 + k] : resW[(size_t)l*4096 + (c-64)*64 + k];
      *(u16*)((char*)Bt + c*128 + ((k*2) ^ ((c&7)<<4))) = f2bf(v);
    }
  }
}

// eeg1_W (23680x256 fp32) -> Wt (256 x 23680 bf16)
__global__ void ktrans(const float* __restrict__ W, u16* __restrict__ Wt){
  __shared__ float tile[64][65];
  int kb = blockIdx.x*64, cb = blockIdx.y*64;
  for(int idx = threadIdx.x; idx < 4096; idx += 256){
    int kk = idx>>6, cc = idx&63;
    tile[kk][cc] = W[(size_t)(kb+kk)*256 + cb+cc];
  }
  __syncthreads();
  for(int idx = threadIdx.x; idx < 4096; idx += 256){
    int cc = idx>>6, kk = idx&63;
    Wt[(size_t)(cb+cc)*23680 + kb+kk] = f2bf(tile[kk][cc]);
  }
}

// ---------- main pipeline kernels ----------
__global__ __launch_bounds__(256) void krowmm_in(const float* __restrict__ X, const u16* __restrict__ Bt,
                                                 const float* __restrict__ bias, float* __restrict__ out){
  __shared__ char sA[8192];
  __shared__ char sB[8192];
  int tid = threadIdx.x;
  copyB(sB, Bt, 8192, tid, 256);
  stageA_f32<false>(sA, X + (size_t)blockIdx.x*4096, tid, 256);
  __syncthreads();
  int w = tid>>6, ln = tid&63;
  f32x4 acc[4];
  mma_core<4,2>(sA, sB, 128, 128, acc, ln, w);
  size_t rbase = (size_t)blockIdx.x*64 + w*16 + ((ln>>4)<<2);
#pragma unroll
  for(int nt=0; nt<4; ++nt){
    int c = nt*16 + (ln&15);
    float bv = bias[c];
#pragma unroll
    for(int r=0;r<4;++r) out[(rbase+r)*64 + c] = acc[nt][r] + bv;
  }
}

// grid (6, BTOT): block = 64 node-rows of one bt. Writes t1T[bt][c=128][node pad 384].
__global__ __launch_bounds__(256) void krowmm_uv(const float* __restrict__ X, const u16* __restrict__ Bt,
                                                 u16* __restrict__ t1T){
  __shared__ char sA[8192];
  __shared__ char sB[16384];
  int nb = blockIdx.x, bt = blockIdx.y, tid = threadIdx.x;
  copyB(sB, Bt, 16384, tid, 256);
  int rows_valid = NN - nb*64; if(rows_valid > 64) rows_valid = 64;
  const float* src = X + ((size_t)bt*NN + nb*64)*64;
  for(int s = tid; s < 512; s += 256){
    int row = s >> 3, ks = s & 7;
    bf16x8 v;
    if(row < rows_valid){
      const float4* p4 = reinterpret_cast<const float4*>(src + row*64 + ks*8);
      float4 a = p4[0], b = p4[1];
      float f[8] = {a.x,a.y,a.z,a.w,b.x,b.y,b.z,b.w};
#pragma unroll
      for(int i=0;i<8;i++) v[i] = (short)f2bf(f[i]);
    } else {
      bf16x8 z = {0,0,0,0,0,0,0,0}; v = z;
    }
    sts16(sA, row, ks*16, 128, v);
  }
  __syncthreads();
  int w = tid>>6, ln = tid&63;
  f32x4 acc[8];
  mma_core<8,2>(sA, sB, 128, 128, acc, ln, w);
  int nd0 = nb*64 + w*16 + ((ln>>4)<<2);        // node base of this 4-row fragment (mult of 4)
  u16* dstb = t1T + (size_t)bt*T1TSTRIDE;
  if(nd0 + 3 < NN){
#pragma unroll
    for(int nt=0; nt<8; ++nt){
      int c = nt*16 + (ln&15);
      s16x4 v;
#pragma unroll
      for(int r=0;r<4;++r) v[r] = (short)f2bf(acc[nt][r]);
      *reinterpret_cast<s16x4*>(dstb + (size_t)c*384 + nd0) = v;
    }
  } else if(nd0 < NN){
#pragma unroll
    for(int nt=0; nt<8; ++nt){
      int c = nt*16 + (ln&15);
#pragma unroll
      for(int r=0;r<4;++r)
        if(nd0 + r < NN) dstb[(size_t)c*384 + nd0 + r] = f2bf(acc[nt][r]);
    }
  }
}

// per-(b,t): OUT(370x64) = A_cat(384x768) @ W_big(768x64), + (gcnf_b + gcna_b)
// W_big rows: k<384 -> U = t1T rows c in [0,64); k>=384 -> V = t1T rows c in [64,128)
__global__ __launch_bounds__(512) void kspmm(const u16* __restrict__ t1T, const u16* __restrict__ Acat,
                                             const float* __restrict__ bfb, const float* __restrict__ bab,
                                             u16* __restrict__ t2){
  __shared__ char uvt[64*768];   // 48KB: one phase of W_big^T [n=64][k=384]
  int bt = blockIdx.x, tid = threadIdx.x;
  int w = tid>>6, ln = tid&63;
  f32x4 acc[12];
#pragma unroll
  for(int j=0;j<12;j++) acc[j] = f32x4{0.f,0.f,0.f,0.f};
  const char* srcb = (const char*)(t1T + (size_t)bt*T1TSTRIDE);
  int srow = tid >> 3, sk0 = (tid & 7) << 4;
  int kboff = (ln>>4)<<4;
  int lr = ln & 15;
  for(int p=0; p<2; ++p){
    __syncthreads();
#pragma unroll
    for(int j=0;j<6;++j){
      int kb = sk0 + j*128;
      bf16x8 v = *reinterpret_cast<const bf16x8*>(srcb + (size_t)(p*64 + srow)*768 + kb);
      sts16(uvt, srow, kb, 768, v);
    }
    __syncthreads();
    const char* abase = (const char*)Acat + p*768 + kboff;
#pragma unroll
    for(int kt=0; kt<12; ++kt){
      bf16x8 a0 = *reinterpret_cast<const bf16x8*>(abase + (size_t)((w*3+0)*16 + lr)*1536 + kt*64);
      bf16x8 a1 = *reinterpret_cast<const bf16x8*>(abase + (size_t)((w*3+1)*16 + lr)*1536 + kt*64);
      bf16x8 a2 = *reinterpret_cast<const bf16x8*>(abase + (size_t)((w*3+2)*16 + lr)*1536 + kt*64);
      bf16x8 b0 = lds16(uvt, 0*16 + lr, kt*64 + kboff, 768);
      bf16x8 b1 = lds16(uvt, 1*16 + lr, kt*64 + kboff, 768);
      bf16x8 b2 = lds16(uvt, 2*16 + lr, kt*64 + kboff, 768);
      bf16x8 b3 = lds16(uvt, 3*16 + lr, kt*64 + kboff, 768);
      acc[0]  = __builtin_amdgcn_mfma_f32_16x16x32_bf16(a0, b0, acc[0],  0,0,0);
      acc[1]  = __builtin_amdgcn_mfma_f32_16x16x32_bf16(a0, b1, acc[1],  0,0,0);
      acc[2]  = __builtin_amdgcn_mfma_f32_16x16x32_bf16(a0, b2, acc[2],  0,0,0);
      acc[3]  = __builtin_amdgcn_mfma_f32_16x16x32_bf16(a0, b3, acc[3],  0,0,0);
      acc[4]  = __builtin_amdgcn_mfma_f32_16x16x32_bf16(a1, b0, acc[4],  0,0,0);
      acc[5]  = __builtin_amdgcn_mfma_f32_16x16x32_bf16(a1, b1, acc[5],  0,0,0);
      acc[6]  = __builtin_amdgcn_mfma_f32_16x16x32_bf16(a1, b2, acc[6],  0,0,0);
      acc[7]  = __builtin_amdgcn_mfma_f32_16x16x32_bf16(a1, b3, acc[7],  0,0,0);
      acc[8]  = __builtin_amdgcn_mfma_f32_16x16x32_bf16(a2, b0, acc[8],  0,0,0);
      acc[9]  = __builtin_amdgcn_mfma_f32_16x16x32_bf16(a2, b1, acc[9],  0,0,0);
      acc[10] = __builtin_amdgcn_mfma_f32_16x16x32_bf16(a2, b2, acc[10], 0,0,0);
      acc[11] = __builtin_amdgcn_mfma_f32_16x16x32_bf16(a2, b3, acc[11], 0,0,0);
    }
  }
#pragma unroll
  for(int mi=0; mi<3; ++mi){
    int mt = w*3 + mi;
    int mbase = mt*16 + ((ln>>4)<<2);
#pragma unroll
    for(int nt=0; nt<4; ++nt){
      int col = nt*16 + lr;
      float bias = bfb[col] + bab[col];
#pragma unroll
      for(int r=0;r<4;++r){
        int m = mbase + r;
        if(m < NN) t2[((size_t)bt*NN + m)*64 + col] = f2bf(acc[mi*4+nt][r] + bias);
      }
    }
  }
}

// gated causal conv: out = tanh(filt)*sigmoid(gate); A rows = [h(t) ; h(t-dil)]
// 512 threads, 128 rows per block
__global__ __launch_bounds__(512) void kconv(const u16* __restrict__ t2, const u16* __restrict__ Bt,
                                             const float* __restrict__ fb, const float* __restrict__ gb,
                                             u16* __restrict__ t3, int dil){
  __shared__ char sA[128*256];   // 32KB
  __shared__ char sB[128*256];   // 32KB
  int blk = blockIdx.x, tid = threadIdx.x;
  copyB(sB, Bt, 32768, tid, 512);
  int r0 = blk*128;
  for(int s = tid; s < 2048; s += 512){
    int row = s >> 4, sc = s & 15;
    int r = r0 + row;
    bf16x8 v;
    if(sc < 8){
      v = *reinterpret_cast<const bf16x8*>(t2 + (size_t)r*64 + sc*8);
    } else {
      int t = (r / NN) % TT;
      if(t >= dil) v = *reinterpret_cast<const bf16x8*>(t2 + (size_t)(r - dil*NN)*64 + (sc-8)*8);
      else { bf16x8 z = {0,0,0,0,0,0,0,0}; v = z; }
    }
    sts16(sA, row, sc*16, 256, v);
  }
  __syncthreads();
  int w = tid>>6, ln = tid&63;
  f32x4 acc[8];
  mma_core<8,4>(sA, sB, 256, 256, acc, ln, w);
  size_t rbase = (size_t)r0 + w*16 + ((ln>>4)<<2);
#pragma unroll
  for(int nt=0; nt<4; ++nt){
    int o = nt*16 + (ln&15);
    float fbv = fb[o], gbv = gb[o];
#pragma unroll
    for(int r=0;r<4;++r){
      float fv = acc[nt][r] + fbv;
      float gv = acc[nt+4][r] + gbv;
      float ov = tanhf(fv) * (1.f/(1.f + expf(-gv)));
      t3[(rbase+r)*64 + o] = f2bf(ov);
    }
  }
}

// fused skip/res 1x1 convs + residual + LayerNorm + skip accumulation.
// LN done entirely in MFMA fragment registers: rows live in 16-lane (lr) groups.
__global__ __launch_bounds__(256) void ksr(const u16* __restrict__ t3, const u16* __restrict__ Bt,
                                           const float* __restrict__ sb, const float* __restrict__ rb,
                                           const float* __restrict__ lng, const float* __restrict__ lnb,
                                           float* __restrict__ xbuf, u16* __restrict__ skip, int first){
  __shared__ char sA[8192];
  __shared__ char sB[16384];
  int tid = threadIdx.x;
  copyB(sB, Bt, 16384, tid, 256);
  stageA_bf16<false>(sA, t3 + (size_t)blockIdx.x*4096, tid, 256);
  __syncthreads();
  int w = tid>>6, ln = tid&63;
  int lr = ln & 15, hi = ln >> 4;
  f32x4 acc[8];
  mma_core<8,2>(sA, sB, 128, 128, acc, ln, w);
  // fragment rows: row = w*16 + hi*4 + r; cols: acc[0..3]=skip (c=nt*16+lr), acc[4..7]=res
  size_t r0 = (size_t)blockIdx.x*64;
  f32x4 y[4];
  f32x4 sum = {0.f,0.f,0.f,0.f}, ssq = {0.f,0.f,0.f,0.f};
#pragma unroll
  for(int nt=0; nt<4; ++nt){
    int col = nt*16 + lr;
    float rbv = rb[col];
#pragma unroll
    for(int r=0;r<4;++r){
      int row = w*16 + hi*4 + r;
      float xo = xbuf[(r0+row)*64 + col];
      float v = acc[4+nt][r] + rbv + xo;
      y[nt][r] = v;
      sum[r] += v;
      ssq[r] += v*v;
    }
  }
  // reduce across the 16 lanes (lr) holding the same rows
#pragma unroll
  for(int o=1;o<16;o<<=1){
#pragma unroll
    for(int r=0;r<4;++r){
      sum[r] += __shfl_xor(sum[r], o, 64);
      ssq[r] += __shfl_xor(ssq[r], o, 64);
    }
  }
  f32x4 mval, rstd;
#pragma unroll
  for(int r=0;r<4;++r){
    float m = sum[r] * (1.f/64.f);
    float var = ssq[r] * (1.f/64.f) - m*m;
    mval[r] = m;
    rstd[r] = rsqrtf(var + 1e-5f);
  }
#pragma unroll
  for(int nt=0; nt<4; ++nt){
    int col = nt*16 + lr;
    float g = lng[col], bb = lnb[col], sbv = sb[col];
#pragma unroll
    for(int r=0;r<4;++r){
      int row = w*16 + hi*4 + r;
      size_t gi = (r0+row)*64 + col;
      xbuf[gi] = (y[nt][r] - mval[r]) * rstd[r] * g + bb;
      float s = acc[nt][r] + sbv;
      if(first) skip[gi] = f2bf(s);
      else      skip[gi] = f2bf(bf2f((short)skip[gi]) + s);
    }
  }
}

__global__ __launch_bounds__(256) void kend_bf16(const u16* __restrict__ X, const u16* __restrict__ Bt,
                                                 const float* __restrict__ bias, u16* __restrict__ out){
  __shared__ char sA[8192];
  __shared__ char sB[8192];
  int tid = threadIdx.x;
  copyB(sB, Bt, 8192, tid, 256);
  stageA_bf16<true>(sA, X + (size_t)blockIdx.x*4096, tid, 256);
  __syncthreads();
  int w = tid>>6, ln = tid&63;
  f32x4 acc[4];
  mma_core<4,2>(sA, sB, 128, 128, acc, ln, w);
  size_t rbase = (size_t)blockIdx.x*64 + w*16 + ((ln>>4)<<2);
#pragma unroll
  for(int nt=0; nt<4; ++nt){
    int c = nt*16 + (ln&15);
    float bv = bias[c];
#pragma unroll
    for(int r=0;r<4;++r) out[(rbase+r)*64 + c] = f2bf(acc[nt][r] + bv);
  }
}

// eeg1: (512 x 23680) @ (23680 x 256), split-K partials (deterministic, no atomics)
__global__ __launch_bounds__(512) void keeg1(const u16* __restrict__ h2, const u16* __restrict__ WtE,
                                             float* __restrict__ part){
  __shared__ char sA[64*128];    // 8KB
  __shared__ char sB[256*128];   // 32KB
  int rowg = blockIdx.x, sp = blockIdx.y;
  int tid = threadIdx.x, w = tid>>6, ln = tid&63;
  f32x4 acc[8];
#pragma unroll
  for(int i=0;i<8;i++) acc[i] = f32x4{0.f,0.f,0.f,0.f};
  int mt = w & 3, ntb = (w>>2)*8;
  for(int ks=0; ks<74; ++ks){
    int k0 = (sp*74 + ks)*32;
    __syncthreads();
    for(int s = tid; s < 256; s += 512){
      int row = s>>2, kc = s&3;
      bf16x8 v = *reinterpret_cast<const bf16x8*>(h2 + (size_t)(rowg*64+row)*23680 + k0 + kc*8);
      sts16(sA, row, kc*16, 128, v);
    }
    for(int s = tid; s < 1024; s += 512){
      int row = s>>2, kc = s&3;
      bf16x8 v = *reinterpret_cast<const bf16x8*>(WtE + (size_t)row*23680 + k0 + kc*8);
      sts16(sB, row, kc*16, 128, v);
    }
    __syncthreads();
    bf16x8 a = lds16(sA, mt*16 + (ln&15), ((ln>>4)<<4), 128);
#pragma unroll
    for(int j=0;j<8;++j){
      bf16x8 b = lds16(sB, (ntb+j)*16 + (ln&15), ((ln>>4)<<4), 128);
      acc[j] = __builtin_amdgcn_mfma_f32_16x16x32_bf16(a, b, acc[j], 0, 0, 0);
    }
  }
  float* dst = part + ((size_t)sp*512 + rowg*64)*256;
#pragma unroll
  for(int j=0;j<8;++j){
    int c = (ntb+j)*16 + (ln&15);
#pragma unroll
    for(int r=0;r<4;++r){
      int row = mt*16 + ((ln>>4)<<2) + r;
      dst[(size_t)row*256 + c] = acc[j][r];
    }
  }
}

// reduce partials + bias + gelu, then @ eeg2_W + b2 -> output (fp32)
__global__ __launch_bounds__(256) void keeg2(const float* __restrict__ part, const float* __restrict__ b1,
                                             const float* __restrict__ W2, const float* __restrict__ b2,
                                             float* __restrict__ out){
  __shared__ float u[256];
  __shared__ float pr[4][64];
  int bt = blockIdx.x, tid = threadIdx.x;
  float sacc = 0.f;
  for(int sp2=0; sp2<SPLITK; ++sp2) sacc += part[((size_t)sp2*512 + bt)*256 + tid];
  u[tid] = gelu_f(sacc + b1[tid]);
  __syncthreads();
  int w = tid>>6, ln = tid&63;
  float acc = 0.f;
  for(int c = w*64; c < (w+1)*64; ++c) acc += u[c] * W2[c*64 + ln];
  pr[w][ln] = acc;
  __syncthreads();
  if(tid < 64)
    out[(size_t)bt*64 + tid] = pr[0][tid]+pr[1][tid]+pr[2][tid]+pr[3][tid] + b2[tid];
}

// ---------- launcher ----------
extern "C" void kernel_launch(void* const* d_in, const int* in_sizes, int n_in,
                              void* d_out, int out_size, void* d_ws, size_t ws_size,
                              hipStream_t stream){
  const float* x_in  = (const float*)d_in[0];
  const int*   ei    = (const int*)d_in[1];
  const float* ew    = (const float*)d_in[2];
  const float* in_W  = (const float*)d_in[3];
  const float* in_b  = (const float*)d_in[4];
  const float* gcnfW = (const float*)d_in[5];
  const float* gcnfb = (const float*)d_in[6];
  const float* esrc  = (const float*)d_in[7];
  const float* etgt  = (const float*)d_in[8];
  const float* gcnaW = (const float*)d_in[9];
  const float* gcnab = (const float*)d_in[10];
  const float* filtW = (const float*)d_in[11];
  const float* filtb = (const float*)d_in[12];
  const float* gateW = (const float*)d_in[13];
  const float* gateb = (const float*)d_in[14];
  const float* resW  = (const float*)d_in[15];
  const float* resb  = (const float*)d_in[16];
  const float* skipW = (const float*)d_in[17];
  const float* skipb = (const float*)d_in[18];
  const float* lng   = (const float*)d_in[19];
  const float* lnb   = (const float*)d_in[20];
  const float* e1W   = (const float*)d_in[21];
  const float* e1b   = (const float*)d_in[22];
  const float* e2W   = (const float*)d_in[23];
  const float* e2b   = (const float*)d_in[24];
  const float* eg1W  = (const float*)d_in[25];
  const float* eg1b  = (const float*)d_in[26];
  const float* eg2W  = (const float*)d_in[27];
  const float* eg2b  = (const float*)d_in[28];
  int E = in_sizes[2];

  char* p = (char*)d_ws;
  auto carve = [&](size_t bytes)->char*{ char* r = p; p += (bytes + 255) & ~(size_t)255; return r; };
  float* xbuf  = (float*)carve((size_t)RR*64*4);
  u16*   skip  = (u16*)  carve((size_t)RR*64*2);
  u16*   t1T   = (u16*)  carve((size_t)BTOT*T1TSTRIDE*2);   // [bt][128][384]
  u16*   t2    = (u16*)  carve((size_t)RR*64*2);
  u16*   t3    = (u16*)  carve((size_t)RR*64*2);
  float* Araw9 = (float*)carve((size_t)9*NN*NN*4);   // [fixed | 8 adaptive raw]
  float* Araw  = Araw9;
  float* ArawA = Araw9 + (size_t)NN*NN;
  float* dinvF = (float*)carve(NN*4);
  float* dinvA = (float*)carve(LL*NN*4);
  u16*   Acat  = (u16*)  carve((size_t)LL*384*768*2);
  u16*   BtUV  = (u16*)  carve((size_t)LL*128*64*2);
  u16*   BtCV  = (u16*)  carve((size_t)LL*128*128*2);
  u16*   BtSR  = (u16*)  carve((size_t)LL*128*64*2);
  u16*   BtIN  = (u16*)  carve(64*64*2);
  u16*   BtE1  = (u16*)  carve(64*64*2);
  u16*   BtE2  = (u16*)  carve(64*64*2);
  u16*   WtE   = (u16*)  carve((size_t)256*23680*2);
  float* part  = (float*)carve((size_t)SPLITK*512*256*4);
  u16* h1 = t1T;                      // overlay: t1T unused after layer loop
  u16* h2 = t1T + (size_t)RR*64;      // fits: BTOT*T1TSTRIDE = 25.2M elems >= 2*RR*64 = 24.2M

  // --- prep ---
  kzero<<<1024, 256, 0, stream>>>(Araw9, (size_t)9*NN*NN);
  kzpad<<<(BTOT*128 + 255)/256, 256, 0, stream>>>(t1T);
  kbuildA<<<(E+255)/256, 256, 0, stream>>>(ei, ew, Araw, E);
  knormF<<<1, 384, 0, stream>>>(Araw, dinvF);
  kadapt<<<dim3(NN, LL), 384, 0, stream>>>(esrc, etgt, ArawA, dinvA);
  kacat<<<(LL*384*768 + 255)/256, 256, 0, stream>>>(Araw, ArawA, dinvF, dinvA, Acat);
  kbt_small<<<3, 256, 0, stream>>>(in_W, e1W, e2W, BtIN, BtE1, BtE2);
  kbt_layer<<<dim3(LL, 3), 256, 0, stream>>>(gcnfW, gcnaW, filtW, gateW, skipW, resW, BtUV, BtCV, BtSR);
  ktrans<<<dim3(370, 4), 256, 0, stream>>>(eg1W, WtE);

  // --- input proj ---
  krowmm_in<<<RR/64, 256, 0, stream>>>(x_in, BtIN, in_b, xbuf);

  // --- layers ---
  for(int l=0; l<LL; ++l){
    int dil = 1 << (l & 3);
    krowmm_uv<<<dim3(6, BTOT), 256, 0, stream>>>(xbuf, BtUV + (size_t)l*8192, t1T);
    kspmm<<<BTOT, 512, 0, stream>>>(t1T, Acat + (size_t)l*384*768, gcnfb + l*64, gcnab + l*64, t2);
    kconv<<<RR/128, 512, 0, stream>>>(t2, BtCV + (size_t)l*16384, filtb + l*64, gateb + l*64, t3, dil);
    ksr<<<RR/64, 256, 0, stream>>>(t3, BtSR + (size_t)l*8192, skipb + l*64, resb + l*64,
                                   lng + l*64, lnb + l*64, xbuf, skip, l==0 ? 1 : 0);
  }

  // --- tail ---
  kend_bf16<<<RR/64, 256, 0, stream>>>(skip, BtE1, e1b, h1);
  kend_bf16<<<RR/64, 256, 0, stream>>>(h1, BtE2, e2b, h2);
  keeg1<<<dim3(8, SPLITK), 512, 0, stream>>>(h2, WtE, part);
  keeg2<<<BTOT, 256, 0, stream>>>(part, eg1b, eg2W, eg2b, (float*)d_out);
}

// Round 4
// 1313.809 us; speedup vs baseline: 1.9704x; 1.0779x over previous
//
#include <hip/hip_runtime.h>
#include <hip/hip_bf16.h>
#include <math.h>

typedef __attribute__((ext_vector_type(8))) short bf16x8;
typedef __attribute__((ext_vector_type(4))) short s16x4;
typedef __attribute__((ext_vector_type(4))) float f32x4;
typedef unsigned short u16;
typedef unsigned int u32;
typedef unsigned long long u64;

#define NN 370
#define HH 64
#define LL 8
#define TT 64
#define BTOT 512            // B*T
#define RR (BTOT*NN)        // 189440 rows
#define KTOPK 37
#define SPLITK 37
#define T1TSTRIDE 49152     // 128*384 elements per bt in t1T

// ---------- helpers ----------
__device__ inline u16 f2bf(float f){
  __hip_bfloat16 h = __float2bfloat16(f);
  return __builtin_bit_cast(u16, h);
}
__device__ inline float bf2f(short s){
  u32 v = ((u32)(u16)s) << 16;
  return __builtin_bit_cast(float, v);
}
__device__ inline float gelu_f(float x){ return 0.5f * x * (1.0f + erff(x * 0.70710678118654752440f)); }

// swizzled LDS store/load of 16B (8 bf16). stride must be a multiple of 128 bytes.
__device__ inline void sts16(char* lds, int row, int kb, int stride, bf16x8 v){
  *reinterpret_cast<bf16x8*>(lds + row*stride + (kb ^ ((row&7)<<4))) = v;
}
__device__ inline bf16x8 lds16(const char* lds, int row, int kb, int stride){
  return *reinterpret_cast<const bf16x8*>(lds + row*stride + (kb ^ ((row&7)<<4)));
}
__device__ inline void copyB(char* dst, const u16* src, int bytes, int tid, int nthr){
  for(int o = tid*16; o < bytes; o += nthr*16)
    *reinterpret_cast<bf16x8*>(dst + o) =
      *reinterpret_cast<const bf16x8*>(reinterpret_cast<const char*>(src) + o);
}

// MFMA core: one 16-row M-tile (mt) x NT 16-col tiles, K = KT*32, A/B both swizzled LDS.
template<int NT, int KT>
__device__ inline void mma_core(const char* sA, const char* sB, int strideA, int strideB,
                                f32x4* acc, int ln, int mt){
#pragma unroll
  for(int nt=0; nt<NT; ++nt) acc[nt] = f32x4{0.f,0.f,0.f,0.f};
#pragma unroll
  for(int kt=0; kt<KT; ++kt){
    int kb = kt*64 + ((ln>>4)<<4);
    bf16x8 a = lds16(sA, mt*16 + (ln&15), kb, strideA);
#pragma unroll
    for(int nt=0; nt<NT; ++nt){
      bf16x8 b = lds16(sB, nt*16 + (ln&15), kb, strideB);
      acc[nt] = __builtin_amdgcn_mfma_f32_16x16x32_bf16(a, b, acc[nt], 0, 0, 0);
    }
  }
}

// stage 64 rows x 64 cols (fp32 source) -> bf16 swizzled LDS, stride 128B
template<bool DOGELU>
__device__ inline void stageA_f32(char* sA, const float* src, int tid, int nthr){
  for(int s = tid; s < 512; s += nthr){
    int row = s >> 3, ks = s & 7;
    const float4* p = reinterpret_cast<const float4*>(src + row*64 + ks*8);
    float4 a = p[0], b = p[1];
    float f[8] = {a.x,a.y,a.z,a.w,b.x,b.y,b.z,b.w};
    if(DOGELU){
#pragma unroll
      for(int i=0;i<8;i++) f[i] = gelu_f(f[i]);
    }
    bf16x8 v;
#pragma unroll
    for(int i=0;i<8;i++) v[i] = (short)f2bf(f[i]);
    sts16(sA, row, ks*16, 128, v);
  }
}
template<bool DOGELU>
__device__ inline void stageA_bf16(char* sA, const u16* src, int tid, int nthr){
  for(int s = tid; s < 512; s += nthr){
    int row = s >> 3, ks = s & 7;
    bf16x8 v = *reinterpret_cast<const bf16x8*>(src + row*64 + ks*8);
    if(DOGELU){
#pragma unroll
      for(int i=0;i<8;i++) v[i] = (short)f2bf(gelu_f(bf2f(v[i])));
    }
    sts16(sA, row, ks*16, 128, v);
  }
}

// ---------- prep kernels ----------
__global__ void kzero(float* __restrict__ p, size_t n){
  for(size_t i = (size_t)blockIdx.x*256 + threadIdx.x; i < n; i += (size_t)gridDim.x*256) p[i] = 0.f;
}

// zero t1T pad nodes [370,384) for every (bt, c) — must run every call
__global__ void kzpad(u16* __restrict__ t1T){
  int idx = blockIdx.x*256 + threadIdx.x;   // 512*128 = 65536 (bt*128 + c)
  if(idx < BTOT*128){
    u16* d = t1T + (size_t)idx*384 + NN;
#pragma unroll
    for(int i=0;i<14;i++) d[i] = 0;
  }
}

__global__ void kbuildA(const int* __restrict__ ei, const float* __restrict__ ew, float* __restrict__ Araw, int E){
  int e = blockIdx.x*256 + threadIdx.x;
  if(e < E){
    int src = ei[e], dst = ei[E + e];
    atomicAdd(&Araw[dst*NN + src], ew[e]);
  }
}

__global__ __launch_bounds__(384) void knormF(float* __restrict__ Araw, float* __restrict__ dinvF){
  int i = threadIdx.x;
  if(i < NN){
    float d0 = Araw[i*NN+i];
    if(d0 == 0.f) Araw[i*NN+i] = 1.f;
    float s = 0.f;
    for(int j=0;j<NN;++j) s += Araw[i*NN+j];
    dinvF[i] = rsqrtf(s);
  }
}

// adaptive adjacency: one block per (row i, layer l).
// Exact jax top_k via bitonic sort of packed (value,index) keys:
// positive-float bits are monotonic; lo-word = ~idx makes ties pick smaller idx first.
__global__ __launch_bounds__(512) void kadapt(const float* __restrict__ esrc, const float* __restrict__ etgt,
                                              float* __restrict__ ArawA, float* __restrict__ dinvA){
  __shared__ float tgT[16][372];   // transposed + padded: conflict-free dot reads
  __shared__ float red[8];
  __shared__ u64 keys[512];
  __shared__ int diagflag;
  int i = blockIdx.x, l = blockIdx.y, tid = threadIdx.x;
  const float* Et = etgt + (size_t)l*NN*16;
  for(int idx = tid; idx < NN*16; idx += 512)
    tgT[idx & 15][idx >> 4] = Et[idx];
  float sr[16];
  const float* Es = esrc + ((size_t)l*NN + i)*16;
#pragma unroll
  for(int k=0;k<16;k++) sr[k] = Es[k];
  if(tid == 0) diagflag = 0;
  __syncthreads();
  bool act = tid < NN;
  float s = 0.f;
  if(act){
    float d = 0.f;
#pragma unroll
    for(int k=0;k<16;k++) d += sr[k]*tgT[k][tid];
    s = fmaxf(d, 0.f);
  }
  float v = act ? s : -1.f;
#pragma unroll
  for(int o=1;o<64;o<<=1) v = fmaxf(v, __shfl_xor(v,o,64));
  if((tid&63)==0) red[tid>>6] = v;
  __syncthreads();
  float mx = red[0];
#pragma unroll
  for(int q=1;q<8;q++) mx = fmaxf(mx, red[q]);
  __syncthreads();
  float e = act ? expf(s - mx) : 0.f;
  float t = e;
#pragma unroll
  for(int o=1;o<64;o<<=1) t += __shfl_xor(t,o,64);
  if((tid&63)==0) red[tid>>6] = t;
  __syncthreads();
  float sum = 0.f;
#pragma unroll
  for(int q=0;q<8;q++) sum += red[q];
  float p = e / sum;
  u32 fb = __builtin_bit_cast(u32, p);
  keys[tid] = act ? ((((u64)fb)<<32) | (u64)(0xFFFFFFFFu - (u32)tid)) : 0ULL;
  __syncthreads();
  // bitonic sort, descending
  for(int k2=2; k2<=512; k2<<=1){
    for(int j=k2>>1; j>0; j>>=1){
      int ixj = tid ^ j;
      if(ixj > tid){
        u64 a = keys[tid], b = keys[ixj];
        bool dirUp = ((tid & k2) == 0);
        if(dirUp ? (a < b) : (a > b)){ keys[tid] = b; keys[ixj] = a; }
      }
      __syncthreads();
    }
  }
  float myval = 0.f; int myidx = -1;
  if(tid < KTOPK){
    u64 kk = keys[tid];
    myidx = (int)(0xFFFFFFFFu - (u32)kk);
    myval = __builtin_bit_cast(float, (u32)(kk>>32));
    if(myidx == i) diagflag = 1;
  }
  __syncthreads();
  float dsum = (tid < KTOPK) ? myval : 0.f;
  if(tid < 64){
#pragma unroll
    for(int o=1;o<64;o<<=1) dsum += __shfl_xor(dsum,o,64);
    if(tid == 0) dinvA[l*NN + i] = rsqrtf(dsum + (diagflag ? 0.f : 1.f));
  }
  if(tid < KTOPK) ArawA[((size_t)l*NN + i)*NN + myidx] = myval;
  if(tid == 0 && !diagflag) ArawA[((size_t)l*NN + i)*NN + i] = 1.f;
}

// build normalized dense bf16 A_cat[l] = [A_fixed(384) | A_adapt(384)] over k=768
__global__ void kacat(const float* __restrict__ Araw, const float* __restrict__ ArawA,
                      const float* __restrict__ dinvF, const float* __restrict__ dinvA,
                      u16* __restrict__ Acat){
  int idx = blockIdx.x*256 + threadIdx.x;
  if(idx >= LL*384*768) return;
  int k = idx % 768; int m = (idx / 768) % 384; int l = idx / (768*384);
  float v = 0.f;
  if(m < NN){
    if(k < 384){
      if(k < NN) v = dinvF[m]*Araw[m*NN+k]*dinvF[k];
    } else {
      int n = k - 384;
      if(n < NN) v = dinvA[l*NN+m]*ArawA[((size_t)l*NN+m)*NN+n]*dinvA[l*NN+n];
    }
  }
  Acat[idx] = f2bf(v);
}

// pre-transposed + pre-swizzled weight tiles Bt[col][k]
__global__ void kbt_small(const float* __restrict__ inW, const float* __restrict__ e1W, const float* __restrict__ e2W,
                          u16* __restrict__ BtIN, u16* __restrict__ BtE1, u16* __restrict__ BtE2){
  const float* W = blockIdx.x==0 ? inW : (blockIdx.x==1 ? e1W : e2W);
  u16* Bt = blockIdx.x==0 ? BtIN : (blockIdx.x==1 ? BtE1 : BtE2);
  for(int idx = threadIdx.x; idx < 4096; idx += 256){
    int c = idx >> 6, k = idx & 63;
    *(u16*)((char*)Bt + c*128 + ((k*2) ^ ((c&7)<<4))) = f2bf(W[k*64 + c]);
  }
}

__global__ void kbt_layer(const float* __restrict__ gcnfW, const float* __restrict__ gcnaW,
                          const float* __restrict__ filtW, const float* __restrict__ gateW,
                          const float* __restrict__ skipW, const float* __restrict__ resW,
                          u16* __restrict__ BtUV, u16* __restrict__ BtCV, u16* __restrict__ BtSR){
  int l = blockIdx.x, which = blockIdx.y;
  if(which == 0){            // [Wf | Wa] : 128 cols x 64 k
    u16* Bt = BtUV + (size_t)l*128*64;
    for(int idx=threadIdx.x; idx<8192; idx+=256){
      int c = idx>>6, k = idx&63;
      float v = (c<64) ? gcnfW[(size_t)l*4096 + k*64 + c] : gcnaW[(size_t)l*4096 + k*64 + (c-64)];
      *(u16*)((char*)Bt + c*128 + ((k*2) ^ ((c&7)<<4))) = f2bf(v);
    }
  } else if(which == 1){     // conv [filt | gate] : 128 cols x 128 k (k<64: cur tap1, k>=64: prev tap0)
    u16* Bt = BtCV + (size_t)l*128*128;
    for(int idx=threadIdx.x; idx<16384; idx+=256){
      int c = idx>>7, k = idx&127;
      const float* W = (c<64) ? filtW : gateW;
      int o = c & 63, ii = k & 63, tap = (k<64) ? 1 : 0;
      float v = W[(size_t)l*8192 + o*128 + ii*2 + tap];
      *(u16*)((char*)Bt + c*256 + ((k*2) ^ ((c&7)<<4))) = f2bf(v);
    }
  } else {                   // [skip | res] : 128 cols x 64 k
    u16* Bt = BtSR + (size_t)l*128*64;
    for(int idx=threadIdx.x; idx<8192; idx+=256){
      int c = idx>>6, k = idx&63;
      float v = (c<64) ? skipW[(size_t)l*4096 + c*64 + k] : resW[(size_t)l*4096 + (c-64)*64 + k];
      *(u16*)((char*)Bt + c*128 + ((k*2) ^ ((c&7)<<4))) = f2bf(v);
    }
  }
}

// eeg1_W (23680x256 fp32) -> Wt (256 x 23680 bf16)
__global__ void ktrans(const float* __restrict__ W, u16* __restrict__ Wt){
  __shared__ float tile[64][65];
  int kb = blockIdx.x*64, cb = blockIdx.y*64;
  for(int idx = threadIdx.x; idx < 4096; idx += 256){
    int kk = idx>>6, cc = idx&63;
    tile[kk][cc] = W[(size_t)(kb+kk)*256 + cb+cc];
  }
  __syncthreads();
  for(int idx = threadIdx.x; idx < 4096; idx += 256){
    int cc = idx>>6, kk = idx&63;
    Wt[(size_t)(cb+cc)*23680 + kb+kk] = f2bf(tile[kk][cc]);
  }
}

// ---------- epilogue helper: transpose-write a2[8] fragments into t1T ----------
__device__ inline void uv_write(u16* __restrict__ t1T, const f32x4* a2, int rbase, int lr){
  int bt0 = rbase / NN;
  int nd0 = rbase - bt0*NN;
  if(nd0 + 3 < NN){
    u16* dst = t1T + (size_t)bt0*T1TSTRIDE + nd0;
#pragma unroll
    for(int nt=0; nt<8; ++nt){
      int c = nt*16 + lr;
      u32 lo = (u32)f2bf(a2[nt][0]) | ((u32)f2bf(a2[nt][1])<<16);
      u32 hi2 = (u32)f2bf(a2[nt][2]) | ((u32)f2bf(a2[nt][3])<<16);
      *(u32*)(dst + (size_t)c*384) = lo;
      *(u32*)(dst + (size_t)c*384 + 2) = hi2;
    }
  } else {
#pragma unroll
    for(int r=0;r<4;++r){
      int rg = rbase + r;
      int btr = rg / NN, ndr = rg - btr*NN;
#pragma unroll
      for(int nt=0; nt<8; ++nt){
        int c = nt*16 + lr;
        t1T[(size_t)btr*T1TSTRIDE + (size_t)c*384 + ndr] = f2bf(a2[nt][r]);
      }
    }
  }
}

// ---------- main pipeline kernels ----------
// input proj + fused layer-0 UV: x = X@inW+b -> xbuf, t1T = (x@[Wf|Wa])^T
__global__ __launch_bounds__(256) void krowmm_in(const float* __restrict__ X, const u16* __restrict__ Bt,
                                                 const u16* __restrict__ BtUV0, const float* __restrict__ bias,
                                                 float* __restrict__ xbuf, u16* __restrict__ t1T){
  __shared__ char sA[8192];
  __shared__ char sB[8192];
  __shared__ char sB2[16384];
  int tid = threadIdx.x;
  copyB(sB, Bt, 8192, tid, 256);
  copyB(sB2, BtUV0, 16384, tid, 256);
  stageA_f32<false>(sA, X + (size_t)blockIdx.x*4096, tid, 256);
  __syncthreads();
  int w = tid>>6, ln = tid&63, lr = ln&15, hi = ln>>4;
  f32x4 acc[4];
  mma_core<4,2>(sA, sB, 128, 128, acc, ln, w);
  size_t r0 = (size_t)blockIdx.x*64;
  u16 xq[4][4];
#pragma unroll
  for(int nt=0; nt<4; ++nt){
    int c = nt*16 + lr;
    float bv = bias[c];
#pragma unroll
    for(int r=0;r<4;++r){
      int row = w*16 + hi*4 + r;
      float vv = acc[nt][r] + bv;
      xbuf[(r0+row)*64 + c] = vv;
      xq[nt][r] = f2bf(vv);
    }
  }
  __syncthreads();
#pragma unroll
  for(int nt=0; nt<4; ++nt){
    int col = nt*16 + lr;
#pragma unroll
    for(int r=0;r<4;++r){
      int row = w*16 + hi*4 + r;
      *(u16*)(sA + row*128 + ((col*2) ^ ((row&7)<<4))) = xq[nt][r];
    }
  }
  __syncthreads();
  f32x4 a2[8];
  mma_core<8,2>(sA, sB2, 128, 128, a2, ln, w);
  uv_write(t1T, a2, (int)r0 + w*16 + hi*4, lr);
}

// per-(b,t): OUT(370x64) = A_cat(384x768) @ W_big(768x64), + (gcnf_b + gcna_b)
__global__ __launch_bounds__(512) void kspmm(const u16* __restrict__ t1T, const u16* __restrict__ Acat,
                                             const float* __restrict__ bfb, const float* __restrict__ bab,
                                             u16* __restrict__ t2){
  __shared__ char uvt[64*768];   // 48KB: one phase of W_big^T [n=64][k=384]
  int bt = blockIdx.x, tid = threadIdx.x;
  int w = tid>>6, ln = tid&63;
  f32x4 acc[12];
#pragma unroll
  for(int j=0;j<12;j++) acc[j] = f32x4{0.f,0.f,0.f,0.f};
  const char* srcb = (const char*)(t1T + (size_t)bt*T1TSTRIDE);
  int srow = tid >> 3, sk0 = (tid & 7) << 4;
  int kboff = (ln>>4)<<4;
  int lr = ln & 15;
  for(int p=0; p<2; ++p){
    __syncthreads();
#pragma unroll
    for(int j=0;j<6;++j){
      int kb = sk0 + j*128;
      bf16x8 v = *reinterpret_cast<const bf16x8*>(srcb + (size_t)(p*64 + srow)*768 + kb);
      sts16(uvt, srow, kb, 768, v);
    }
    __syncthreads();
    const char* abase = (const char*)Acat + p*768 + kboff;
#pragma unroll
    for(int kt=0; kt<12; ++kt){
      bf16x8 a0 = *reinterpret_cast<const bf16x8*>(abase + (size_t)((w*3+0)*16 + lr)*1536 + kt*64);
      bf16x8 a1 = *reinterpret_cast<const bf16x8*>(abase + (size_t)((w*3+1)*16 + lr)*1536 + kt*64);
      bf16x8 a2 = *reinterpret_cast<const bf16x8*>(abase + (size_t)((w*3+2)*16 + lr)*1536 + kt*64);
      bf16x8 b0 = lds16(uvt, 0*16 + lr, kt*64 + kboff, 768);
      bf16x8 b1 = lds16(uvt, 1*16 + lr, kt*64 + kboff, 768);
      bf16x8 b2 = lds16(uvt, 2*16 + lr, kt*64 + kboff, 768);
      bf16x8 b3 = lds16(uvt, 3*16 + lr, kt*64 + kboff, 768);
      acc[0]  = __builtin_amdgcn_mfma_f32_16x16x32_bf16(a0, b0, acc[0],  0,0,0);
      acc[1]  = __builtin_amdgcn_mfma_f32_16x16x32_bf16(a0, b1, acc[1],  0,0,0);
      acc[2]  = __builtin_amdgcn_mfma_f32_16x16x32_bf16(a0, b2, acc[2],  0,0,0);
      acc[3]  = __builtin_amdgcn_mfma_f32_16x16x32_bf16(a0, b3, acc[3],  0,0,0);
      acc[4]  = __builtin_amdgcn_mfma_f32_16x16x32_bf16(a1, b0, acc[4],  0,0,0);
      acc[5]  = __builtin_amdgcn_mfma_f32_16x16x32_bf16(a1, b1, acc[5],  0,0,0);
      acc[6]  = __builtin_amdgcn_mfma_f32_16x16x32_bf16(a1, b2, acc[6],  0,0,0);
      acc[7]  = __builtin_amdgcn_mfma_f32_16x16x32_bf16(a1, b3, acc[7],  0,0,0);
      acc[8]  = __builtin_amdgcn_mfma_f32_16x16x32_bf16(a2, b0, acc[8],  0,0,0);
      acc[9]  = __builtin_amdgcn_mfma_f32_16x16x32_bf16(a2, b1, acc[9],  0,0,0);
      acc[10] = __builtin_amdgcn_mfma_f32_16x16x32_bf16(a2, b2, acc[10], 0,0,0);
      acc[11] = __builtin_amdgcn_mfma_f32_16x16x32_bf16(a2, b3, acc[11], 0,0,0);
    }
  }
#pragma unroll
  for(int mi=0; mi<3; ++mi){
    int mt = w*3 + mi;
    int mbase = mt*16 + ((ln>>4)<<2);
#pragma unroll
    for(int nt=0; nt<4; ++nt){
      int col = nt*16 + lr;
      float bias = bfb[col] + bab[col];
#pragma unroll
      for(int r=0;r<4;++r){
        int m = mbase + r;
        if(m < NN) t2[((size_t)bt*NN + m)*64 + col] = f2bf(acc[mi*4+nt][r] + bias);
      }
    }
  }
}

// gated causal conv: out = tanh(filt)*sigmoid(gate); A rows = [h(t) ; h(t-dil)]
__global__ __launch_bounds__(512) void kconv(const u16* __restrict__ t2, const u16* __restrict__ Bt,
                                             const float* __restrict__ fb, const float* __restrict__ gb,
                                             u16* __restrict__ t3, int dil){
  __shared__ char sA[128*256];   // 32KB
  __shared__ char sB[128*256];   // 32KB
  int blk = blockIdx.x, tid = threadIdx.x;
  copyB(sB, Bt, 32768, tid, 512);
  int r0 = blk*128;
  for(int s = tid; s < 2048; s += 512){
    int row = s >> 4, sc = s & 15;
    int r = r0 + row;
    bf16x8 v;
    if(sc < 8){
      v = *reinterpret_cast<const bf16x8*>(t2 + (size_t)r*64 + sc*8);
    } else {
      int t = (r / NN) % TT;
      if(t >= dil) v = *reinterpret_cast<const bf16x8*>(t2 + (size_t)(r - dil*NN)*64 + (sc-8)*8);
      else { bf16x8 z = {0,0,0,0,0,0,0,0}; v = z; }
    }
    sts16(sA, row, sc*16, 256, v);
  }
  __syncthreads();
  int w = tid>>6, ln = tid&63;
  f32x4 acc[8];
  mma_core<8,4>(sA, sB, 256, 256, acc, ln, w);
  size_t rbase = (size_t)r0 + w*16 + ((ln>>4)<<2);
#pragma unroll
  for(int nt=0; nt<4; ++nt){
    int o = nt*16 + (ln&15);
    float fbv = fb[o], gbv = gb[o];
#pragma unroll
    for(int r=0;r<4;++r){
      float fv = acc[nt][r] + fbv;
      float gv = acc[nt+4][r] + gbv;
      float ov = tanhf(fv) * (1.f/(1.f + expf(-gv)));
      t3[(rbase+r)*64 + o] = f2bf(ov);
    }
  }
}

// fused skip/res 1x1 convs + residual + LayerNorm + skip accumulation
// + next-layer UV projection (t1T transpose-write) when douv.
__global__ __launch_bounds__(256) void ksr(const u16* __restrict__ t3, const u16* __restrict__ Bt,
                                           const u16* __restrict__ BtUVn,
                                           const float* __restrict__ sb, const float* __restrict__ rb,
                                           const float* __restrict__ lng, const float* __restrict__ lnb,
                                           float* __restrict__ xbuf, u16* __restrict__ skip,
                                           u16* __restrict__ t1T, int first, int douv){
  __shared__ char sA[8192];
  __shared__ char sB[16384];
  __shared__ char sB2[16384];
  int tid = threadIdx.x;
  copyB(sB, Bt, 16384, tid, 256);
  if(douv) copyB(sB2, BtUVn, 16384, tid, 256);
  stageA_bf16<false>(sA, t3 + (size_t)blockIdx.x*4096, tid, 256);
  __syncthreads();
  int w = tid>>6, ln = tid&63, lr = ln&15, hi = ln>>4;
  f32x4 acc[8];
  mma_core<8,2>(sA, sB, 128, 128, acc, ln, w);
  size_t r0 = (size_t)blockIdx.x*64;
  f32x4 y[4];
  f32x4 sum = {0.f,0.f,0.f,0.f}, ssq = {0.f,0.f,0.f,0.f};
#pragma unroll
  for(int nt=0; nt<4; ++nt){
    int col = nt*16 + lr;
    float rbv = rb[col];
#pragma unroll
    for(int r=0;r<4;++r){
      int row = w*16 + hi*4 + r;
      float xo = xbuf[(r0+row)*64 + col];
      float vv = acc[4+nt][r] + rbv + xo;
      y[nt][r] = vv; sum[r] += vv; ssq[r] += vv*vv;
    }
  }
#pragma unroll
  for(int o=1;o<16;o<<=1){
#pragma unroll
    for(int r=0;r<4;++r){
      sum[r] += __shfl_xor(sum[r], o, 64);
      ssq[r] += __shfl_xor(ssq[r], o, 64);
    }
  }
  f32x4 mval, rstd;
#pragma unroll
  for(int r=0;r<4;++r){
    float m = sum[r] * (1.f/64.f);
    float var = ssq[r] * (1.f/64.f) - m*m;
    mval[r] = m; rstd[r] = rsqrtf(var + 1e-5f);
  }
  u16 xq[4][4];
#pragma unroll
  for(int nt=0; nt<4; ++nt){
    int col = nt*16 + lr;
    float g = lng[col], bb = lnb[col], sbv = sb[col];
#pragma unroll
    for(int r=0;r<4;++r){
      int row = w*16 + hi*4 + r;
      size_t gi = (r0+row)*64 + col;
      float xo = (y[nt][r] - mval[r]) * rstd[r] * g + bb;
      if(douv) xbuf[gi] = xo;
      float s = acc[nt][r] + sbv;
      if(first) skip[gi] = f2bf(s);
      else      skip[gi] = f2bf(bf2f((short)skip[gi]) + s);
      xq[nt][r] = f2bf(xo);
    }
  }
  if(!douv) return;
  __syncthreads();
#pragma unroll
  for(int nt=0; nt<4; ++nt){
    int col = nt*16 + lr;
#pragma unroll
    for(int r=0;r<4;++r){
      int row = w*16 + hi*4 + r;
      *(u16*)(sA + row*128 + ((col*2) ^ ((row&7)<<4))) = xq[nt][r];
    }
  }
  __syncthreads();
  f32x4 a2[8];
  mma_core<8,2>(sA, sB2, 128, 128, a2, ln, w);
  uv_write(t1T, a2, (int)r0 + w*16 + hi*4, lr);
}

// fused end convs: h2 = gelu(gelu(skip)@E1 + b1)@E2 + b2
__global__ __launch_bounds__(256) void kend2(const u16* __restrict__ skip, const u16* __restrict__ Bt1,
                                             const u16* __restrict__ Bt2, const float* __restrict__ b1,
                                             const float* __restrict__ b2, u16* __restrict__ h2){
  __shared__ char sA[8192];
  __shared__ char sB1[8192];
  __shared__ char sB2[8192];
  int tid = threadIdx.x;
  copyB(sB1, Bt1, 8192, tid, 256);
  copyB(sB2, Bt2, 8192, tid, 256);
  stageA_bf16<true>(sA, skip + (size_t)blockIdx.x*4096, tid, 256);
  __syncthreads();
  int w = tid>>6, ln = tid&63, lr = ln&15, hi = ln>>4;
  f32x4 acc[4];
  mma_core<4,2>(sA, sB1, 128, 128, acc, ln, w);
  u16 xq[4][4];
#pragma unroll
  for(int nt=0; nt<4; ++nt){
    int c = nt*16 + lr;
    float bv = b1[c];
#pragma unroll
    for(int r=0;r<4;++r) xq[nt][r] = f2bf(gelu_f(acc[nt][r] + bv));
  }
  __syncthreads();
#pragma unroll
  for(int nt=0; nt<4; ++nt){
    int col = nt*16 + lr;
#pragma unroll
    for(int r=0;r<4;++r){
      int row = w*16 + hi*4 + r;
      *(u16*)(sA + row*128 + ((col*2) ^ ((row&7)<<4))) = xq[nt][r];
    }
  }
  __syncthreads();
  f32x4 a2[4];
  mma_core<4,2>(sA, sB2, 128, 128, a2, ln, w);
  size_t rbase = (size_t)blockIdx.x*64 + w*16 + hi*4;
#pragma unroll
  for(int nt=0; nt<4; ++nt){
    int c = nt*16 + lr;
    float bv = b2[c];
#pragma unroll
    for(int r=0;r<4;++r) h2[(rbase+r)*64 + c] = f2bf(a2[nt][r] + bv);
  }
}

// eeg1: (512 x 23680) @ (23680 x 256), split-K partials (deterministic, no atomics)
__global__ __launch_bounds__(512) void keeg1(const u16* __restrict__ h2, const u16* __restrict__ WtE,
                                             float* __restrict__ part){
  __shared__ char sA[64*128];    // 8KB
  __shared__ char sB[256*128];   // 32KB
  int rowg = blockIdx.x, sp = blockIdx.y;
  int tid = threadIdx.x, w = tid>>6, ln = tid&63;
  f32x4 acc[8];
#pragma unroll
  for(int i=0;i<8;i++) acc[i] = f32x4{0.f,0.f,0.f,0.f};
  int mt = w & 3, ntb = (w>>2)*8;
  for(int ks=0; ks<20; ++ks){
    int k0 = (sp*20 + ks)*32;
    __syncthreads();
    for(int s = tid; s < 256; s += 512){
      int row = s>>2, kc = s&3;
      bf16x8 v = *reinterpret_cast<const bf16x8*>(h2 + (size_t)(rowg*64+row)*23680 + k0 + kc*8);
      sts16(sA, row, kc*16, 128, v);
    }
    for(int s = tid; s < 1024; s += 512){
      int row = s>>2, kc = s&3;
      bf16x8 v = *reinterpret_cast<const bf16x8*>(WtE + (size_t)row*23680 + k0 + kc*8);
      sts16(sB, row, kc*16, 128, v);
    }
    __syncthreads();
    bf16x8 a = lds16(sA, mt*16 + (ln&15), ((ln>>4)<<4), 128);
#pragma unroll
    for(int j=0;j<8;++j){
      bf16x8 b = lds16(sB, (ntb+j)*16 + (ln&15), ((ln>>4)<<4), 128);
      acc[j] = __builtin_amdgcn_mfma_f32_16x16x32_bf16(a, b, acc[j], 0, 0, 0);
    }
  }
  float* dst = part + ((size_t)sp*512 + rowg*64)*256;
#pragma unroll
  for(int j=0;j<8;++j){
    int c = (ntb+j)*16 + (ln&15);
#pragma unroll
    for(int r=0;r<4;++r){
      int row = mt*16 + ((ln>>4)<<2) + r;
      dst[(size_t)row*256 + c] = acc[j][r];
    }
  }
}

// reduce partials + bias + gelu, then @ eeg2_W + b2 -> output (fp32)
__global__ __launch_bounds__(256) void keeg2(const float* __restrict__ part, const float* __restrict__ b1,
                                             const float* __restrict__ W2, const float* __restrict__ b2,
                                             float* __restrict__ out){
  __shared__ float u[256];
  __shared__ float pr[4][64];
  int bt = blockIdx.x, tid = threadIdx.x;
  float sacc = 0.f;
  for(int sp2=0; sp2<SPLITK; ++sp2) sacc += part[((size_t)sp2*512 + bt)*256 + tid];
  u[tid] = gelu_f(sacc + b1[tid]);
  __syncthreads();
  int w = tid>>6, ln = tid&63;
  float acc = 0.f;
  for(int c = w*64; c < (w+1)*64; ++c) acc += u[c] * W2[c*64 + ln];
  pr[w][ln] = acc;
  __syncthreads();
  if(tid < 64)
    out[(size_t)bt*64 + tid] = pr[0][tid]+pr[1][tid]+pr[2][tid]+pr[3][tid] + b2[tid];
}

// ---------- launcher ----------
extern "C" void kernel_launch(void* const* d_in, const int* in_sizes, int n_in,
                              void* d_out, int out_size, void* d_ws, size_t ws_size,
                              hipStream_t stream){
  const float* x_in  = (const float*)d_in[0];
  const int*   ei    = (const int*)d_in[1];
  const float* ew    = (const float*)d_in[2];
  const float* in_W  = (const float*)d_in[3];
  const float* in_b  = (const float*)d_in[4];
  const float* gcnfW = (const float*)d_in[5];
  const float* gcnfb = (const float*)d_in[6];
  const float* esrc  = (const float*)d_in[7];
  const float* etgt  = (const float*)d_in[8];
  const float* gcnaW = (const float*)d_in[9];
  const float* gcnab = (const float*)d_in[10];
  const float* filtW = (const float*)d_in[11];
  const float* filtb = (const float*)d_in[12];
  const float* gateW = (const float*)d_in[13];
  const float* gateb = (const float*)d_in[14];
  const float* resW  = (const float*)d_in[15];
  const float* resb  = (const float*)d_in[16];
  const float* skipW = (const float*)d_in[17];
  const float* skipb = (const float*)d_in[18];
  const float* lng   = (const float*)d_in[19];
  const float* lnb   = (const float*)d_in[20];
  const float* e1W   = (const float*)d_in[21];
  const float* e1b   = (const float*)d_in[22];
  const float* e2W   = (const float*)d_in[23];
  const float* e2b   = (const float*)d_in[24];
  const float* eg1W  = (const float*)d_in[25];
  const float* eg1b  = (const float*)d_in[26];
  const float* eg2W  = (const float*)d_in[27];
  const float* eg2b  = (const float*)d_in[28];
  int E = in_sizes[2];

  char* p = (char*)d_ws;
  auto carve = [&](size_t bytes)->char*{ char* r = p; p += (bytes + 255) & ~(size_t)255; return r; };
  float* xbuf  = (float*)carve((size_t)RR*64*4);
  u16*   skip  = (u16*)  carve((size_t)RR*64*2);
  u16*   t1T   = (u16*)  carve((size_t)BTOT*T1TSTRIDE*2);   // [bt][128][384]
  u16*   t2    = (u16*)  carve((size_t)RR*64*2);
  u16*   t3    = (u16*)  carve((size_t)RR*64*2);
  float* Araw9 = (float*)carve((size_t)9*NN*NN*4);   // [fixed | 8 adaptive raw]
  float* Araw  = Araw9;
  float* ArawA = Araw9 + (size_t)NN*NN;
  float* dinvF = (float*)carve(NN*4);
  float* dinvA = (float*)carve(LL*NN*4);
  u16*   Acat  = (u16*)  carve((size_t)LL*384*768*2);
  u16*   BtUV  = (u16*)  carve((size_t)LL*128*64*2);
  u16*   BtCV  = (u16*)  carve((size_t)LL*128*128*2);
  u16*   BtSR  = (u16*)  carve((size_t)LL*128*64*2);
  u16*   BtIN  = (u16*)  carve(64*64*2);
  u16*   BtE1  = (u16*)  carve(64*64*2);
  u16*   BtE2  = (u16*)  carve(64*64*2);
  u16*   WtE   = (u16*)  carve((size_t)256*23680*2);
  float* part  = (float*)carve((size_t)SPLITK*512*256*4);
  u16* h2 = t1T + (size_t)RR*64;      // overlay: t1T free after layers; fits 25.2M >= 2*12.1M

  // --- prep ---
  kzero<<<1024, 256, 0, stream>>>(Araw9, (size_t)9*NN*NN);
  kzpad<<<(BTOT*128 + 255)/256, 256, 0, stream>>>(t1T);
  kbuildA<<<(E+255)/256, 256, 0, stream>>>(ei, ew, Araw, E);
  knormF<<<1, 384, 0, stream>>>(Araw, dinvF);
  kadapt<<<dim3(NN, LL), 512, 0, stream>>>(esrc, etgt, ArawA, dinvA);
  kacat<<<(LL*384*768 + 255)/256, 256, 0, stream>>>(Araw, ArawA, dinvF, dinvA, Acat);
  kbt_small<<<3, 256, 0, stream>>>(in_W, e1W, e2W, BtIN, BtE1, BtE2);
  kbt_layer<<<dim3(LL, 3), 256, 0, stream>>>(gcnfW, gcnaW, filtW, gateW, skipW, resW, BtUV, BtCV, BtSR);
  ktrans<<<dim3(370, 4), 256, 0, stream>>>(eg1W, WtE);

  // --- input proj (+ layer-0 UV) ---
  krowmm_in<<<RR/64, 256, 0, stream>>>(x_in, BtIN, BtUV, in_b, xbuf, t1T);

  // --- layers ---
  for(int l=0; l<LL; ++l){
    int dil = 1 << (l & 3);
    kspmm<<<BTOT, 512, 0, stream>>>(t1T, Acat + (size_t)l*384*768, gcnfb + l*64, gcnab + l*64, t2);
    kconv<<<RR/128, 512, 0, stream>>>(t2, BtCV + (size_t)l*16384, filtb + l*64, gateb + l*64, t3, dil);
    int douv = (l < LL-1) ? 1 : 0;
    ksr<<<RR/64, 256, 0, stream>>>(t3, BtSR + (size_t)l*8192, BtUV + (size_t)((l+1)&7)*8192,
                                   skipb + l*64, resb + l*64,
                                   lng + l*64, lnb + l*64, xbuf, skip, t1T, l==0 ? 1 : 0, douv);
  }

  // --- tail ---
  kend2<<<RR/64, 256, 0, stream>>>(skip, BtE1, BtE2, e1b, e2b, h2);
  keeg1<<<dim3(8, SPLITK), 512, 0, stream>>>(h2, WtE, part);
  keeg2<<<BTOT, 256, 0, stream>>>(part, eg1b, eg2W, eg2b, (float*)d_out);
}